// Round 3
// baseline (972.643 us; speedup 1.0000x reference)
//
#include <hip/hip_runtime.h>
#include <hip/hip_bf16.h>
#include <stdint.h>

#define D_IN 256
#define D_H  97
#define TS   98      // padded row stride (floats) for t/h buffers; col 97 is a zero pad
#define WPAD 128     // padded weight column count

// ---------- helpers ----------
__device__ __forceinline__ int load_idx(const void* p, int is64, long long pos) {
  if (is64) return (int)(((const long long*)p)[pos]);
  return ((const int*)p)[pos];
}

// Decide whether edge_index arrived as int64 (odd 32-bit words all zero) or int32.
__global__ void detect_kernel(const void* ei, long long E, int* flag) {
  const int* p32 = (const int*)ei;
  long long stride = E / 1024; if (stride < 1) stride = 1;
  int tid = threadIdx.x;
  int bad = 0;
  for (int s = 0; s < 4; ++s) {
    long long k = ((long long)tid * 4 + s) * stride;
    if (k < E) {
      if (p32[2 * k + 1] != 0) bad = 1;   // stay within first E int64 slots: in-bounds for both layouts
    }
  }
  __shared__ int sh_bad;
  if (tid == 0) sh_bad = 0;
  __syncthreads();
  if (bad) atomicOr(&sh_bad, 1);
  __syncthreads();
  if (tid == 0) *flag = sh_bad ? 0 : 1;   // 1 => int64
}

__global__ void count_kernel(const void* ei, const int* __restrict__ flag,
                             int* __restrict__ cnt, long long E) {
  long long e = (long long)blockIdx.x * blockDim.x + threadIdx.x;
  if (e >= E) return;
  int f = *flag;
  int d = load_idx(ei, f, E + e);
  atomicAdd(&cnt[d], 1);
}

__global__ void dinv_kernel(const int* __restrict__ cnt, float* __restrict__ dinv, int N) {
  int i = blockIdx.x * blockDim.x + threadIdx.x;
  if (i >= N) return;
  dinv[i] = rsqrtf((float)(cnt[i] + 1));   // +1 self-loop; deg >= 1 always
}

// ---------- exclusive scan over cnt -> row_start (3 phases) ----------
__global__ void scan_a(const int* __restrict__ cnt, int* __restrict__ bsum, int N) {
  int b = blockIdx.x, tid = threadIdx.x;
  int lane = tid & 63, wid = tid >> 6;
  int base = b * 1024 + tid * 4;
  int v0 = (base + 0 < N) ? cnt[base + 0] : 0;
  int v1 = (base + 1 < N) ? cnt[base + 1] : 0;
  int v2 = (base + 2 < N) ? cnt[base + 2] : 0;
  int v3 = (base + 3 < N) ? cnt[base + 3] : 0;
  int t = v0 + v1 + v2 + v3;
  #pragma unroll
  for (int off = 32; off > 0; off >>= 1) t += __shfl_down(t, off, 64);
  __shared__ int sh[4];
  if (lane == 0) sh[wid] = t;
  __syncthreads();
  if (tid == 0) bsum[b] = sh[0] + sh[1] + sh[2] + sh[3];
}

__global__ void scan_b(int* __restrict__ bsum, int NB) {
  __shared__ int sh[1024];
  int tid = threadIdx.x;
  int v = (tid < NB) ? bsum[tid] : 0;
  sh[tid] = v;
  __syncthreads();
  for (int off = 1; off < 1024; off <<= 1) {
    int a = (tid >= off) ? sh[tid - off] : 0;
    __syncthreads();
    sh[tid] += a;
    __syncthreads();
  }
  if (tid < NB) bsum[tid] = sh[tid] - v;   // exclusive block offsets
}

__global__ void scan_c(const int* __restrict__ cnt, const int* __restrict__ bsum,
                       int* __restrict__ row_start, int* __restrict__ cursor,
                       int N, long long E_total) {
  int b = blockIdx.x, tid = threadIdx.x;
  int lane = tid & 63, wid = tid >> 6;
  int base = b * 1024 + tid * 4;
  int v0 = (base + 0 < N) ? cnt[base + 0] : 0;
  int v1 = (base + 1 < N) ? cnt[base + 1] : 0;
  int v2 = (base + 2 < N) ? cnt[base + 2] : 0;
  int v3 = (base + 3 < N) ? cnt[base + 3] : 0;
  int tsum = v0 + v1 + v2 + v3;
  int incl = tsum;
  #pragma unroll
  for (int off = 1; off < 64; off <<= 1) {
    int n = __shfl_up(incl, off, 64);
    if (lane >= off) incl += n;
  }
  __shared__ int wsum[4];
  if (lane == 63) wsum[wid] = incl;
  __syncthreads();
  int woff = 0;
  for (int k = 0; k < wid; ++k) woff += wsum[k];
  int excl = woff + incl - tsum + bsum[b];
  if (base + 0 < N) { row_start[base + 0] = excl;                cursor[base + 0] = excl; }
  if (base + 1 < N) { row_start[base + 1] = excl + v0;           cursor[base + 1] = excl + v0; }
  if (base + 2 < N) { row_start[base + 2] = excl + v0 + v1;      cursor[base + 2] = excl + v0 + v1; }
  if (base + 3 < N) { row_start[base + 3] = excl + v0 + v1 + v2; cursor[base + 3] = excl + v0 + v1 + v2; }
  if (b == 0 && tid == 0) row_start[N] = (int)E_total;
}

// fill: scatter only the source index (weights are folded into t via dinv)
__global__ void fill_kernel(const void* ei, const int* __restrict__ flag,
                            int* __restrict__ cursor,
                            int* __restrict__ csr_src, long long E) {
  long long e = (long long)blockIdx.x * blockDim.x + threadIdx.x;
  if (e >= E) return;
  int f = *flag;
  int s = load_idx(ei, f, e);
  int d = load_idx(ei, f, E + e);
  int pos = atomicAdd(&cursor[d], 1);
  csr_src[pos] = s;
}

// ---------- pad weights/biases into WPAD-wide zero-padded buffers ----------
__global__ void prep_kernel(const float* __restrict__ W1, const float* __restrict__ b1,
                            const float* __restrict__ W2, const float* __restrict__ b2,
                            float* __restrict__ W1p, float* __restrict__ W2p,
                            float* __restrict__ b1p, float* __restrict__ b2p) {
  int idx = blockIdx.x * blockDim.x + threadIdx.x;
  const int n1 = 256 * WPAD, n2 = 112 * WPAD;
  if (idx < n1) {
    int k = idx / WPAD, c = idx % WPAD;
    W1p[idx] = (c < D_H) ? W1[k * D_H + c] : 0.0f;
  } else if (idx < n1 + n2) {
    int j = idx - n1; int k = j / WPAD, c = j % WPAD;
    W2p[j] = (k < D_H && c < D_H) ? W2[k * D_H + c] : 0.0f;
  } else if (idx < n1 + n2 + TS) {
    int c = idx - (n1 + n2);
    b1p[c] = (c < D_H) ? b1[c] : 0.0f;
  } else if (idx < n1 + n2 + 2 * TS) {
    int c = idx - (n1 + n2 + TS);
    b2p[c] = (c < D_H) ? b2[c] : 0.0f;
  }
}

// ---------- f32 tiled GEMM: C[N x TS(pad)] = (A[N x lda] * Wp[K x WPAD]) * dinv[row] ----------
template<int K, int KEFF>
__global__ __launch_bounds__(256) void gemm_kernel(const float* __restrict__ A, int lda,
                                                   const float* __restrict__ Wp,
                                                   const float* __restrict__ dinv,
                                                   float* __restrict__ C, int N) {
  __shared__ float As[16][64];
  __shared__ float Ws[16][128];
  int tid = threadIdx.x;
  int row0 = blockIdx.x * 64;
  int tx = tid & 15, ty = tid >> 4;
  float acc[4][8];
  #pragma unroll
  for (int i = 0; i < 4; ++i)
    #pragma unroll
    for (int j = 0; j < 8; ++j) acc[i][j] = 0.0f;

  int ar  = tid >> 2;          // 0..63 row within tile
  int akq = (tid & 3) * 4;     // k offset 0,4,8,12
  int wc  = (tid & 31) * 4;    // 0..124
  int wk  = tid >> 5;          // 0..7

  for (int kb = 0; kb < K; kb += 16) {
    float2 a01 = make_float2(0.f, 0.f), a23 = make_float2(0.f, 0.f);
    int arow = row0 + ar;
    int k0 = kb + akq;
    if (arow < N) {
      if (k0 < KEFF)     a01 = *(const float2*)&A[(size_t)arow * lda + k0];
      if (k0 + 2 < KEFF) a23 = *(const float2*)&A[(size_t)arow * lda + k0 + 2];
    }
    As[akq + 0][ar] = a01.x; As[akq + 1][ar] = a01.y;
    As[akq + 2][ar] = a23.x; As[akq + 3][ar] = a23.y;
    *(float4*)&Ws[wk][wc]     = *(const float4*)&Wp[(size_t)(kb + wk) * WPAD + wc];
    *(float4*)&Ws[wk + 8][wc] = *(const float4*)&Wp[(size_t)(kb + wk + 8) * WPAD + wc];
    __syncthreads();
    #pragma unroll
    for (int k = 0; k < 16; ++k) {
      float4 a4 = *(const float4*)&As[k][ty * 4];
      float4 wA = *(const float4*)&Ws[k][tx * 4];
      float4 wB = *(const float4*)&Ws[k][64 + tx * 4];
      float av[4] = {a4.x, a4.y, a4.z, a4.w};
      float wv[8] = {wA.x, wA.y, wA.z, wA.w, wB.x, wB.y, wB.z, wB.w};
      #pragma unroll
      for (int i = 0; i < 4; ++i)
        #pragma unroll
        for (int j = 0; j < 8; ++j) acc[i][j] += av[i] * wv[j];
    }
    __syncthreads();
  }
  #pragma unroll
  for (int i = 0; i < 4; ++i) {
    int r = row0 + ty * 4 + i;
    if (r >= N) continue;
    float dv = dinv[r];
    float* crow = C + (size_t)r * TS;
    int cA = tx * 4, cB = 64 + tx * 4;
    *(float2*)&crow[cA]     = make_float2(acc[i][0] * dv, acc[i][1] * dv);
    *(float2*)&crow[cA + 2] = make_float2(acc[i][2] * dv, acc[i][3] * dv);
    if (cB < TS)     *(float2*)&crow[cB]     = make_float2(acc[i][4] * dv, acc[i][5] * dv);
    if (cB + 2 < TS) *(float2*)&crow[cB + 2] = make_float2(acc[i][6] * dv, acc[i][7] * dv);
  }
}

// ---------- CSR aggregation: one wave per destination node, pure row-sum ----------
// t rows are pre-scaled by dinv[src]; final scale by dinv[node] here.
__global__ __launch_bounds__(256) void agg_kernel(
    const float* __restrict__ t, const int* __restrict__ csr_src,
    const int* __restrict__ row_start,
    const float* __restrict__ dinv, const float* __restrict__ bias,
    float* __restrict__ outp, int N, int ostride, int do_relu) {
  int lane = threadIdx.x & 63;
  int node = blockIdx.x * (blockDim.x >> 6) + (threadIdx.x >> 6);
  if (node >= N || lane >= 49) return;   // 49 lanes x float2 = 98 cols (col 97 is zero pad)
  int s = row_start[node], epd = row_start[node + 1];
  float di = dinv[node];
  float2 v = ((const float2*)(t + (size_t)node * TS))[lane];  // self term (already ×dinv[node])
  float ax = v.x, ay = v.y;
  int e = s;
  for (; e + 4 <= epd; e += 4) {
    int j0 = csr_src[e], j1 = csr_src[e + 1], j2 = csr_src[e + 2], j3 = csr_src[e + 3];
    float2 u0 = ((const float2*)(t + (size_t)j0 * TS))[lane];
    float2 u1 = ((const float2*)(t + (size_t)j1 * TS))[lane];
    float2 u2 = ((const float2*)(t + (size_t)j2 * TS))[lane];
    float2 u3 = ((const float2*)(t + (size_t)j3 * TS))[lane];
    ax += u0.x; ay += u0.y;
    ax += u1.x; ay += u1.y;
    ax += u2.x; ay += u2.y;
    ax += u3.x; ay += u3.y;
  }
  for (; e < epd; ++e) {
    int j = csr_src[e];
    float2 u = ((const float2*)(t + (size_t)j * TS))[lane];
    ax += u.x; ay += u.y;
  }
  int c0 = 2 * lane, c1 = 2 * lane + 1;
  ax = ax * di + bias[c0];
  ay = ay * di + bias[c1];
  if (do_relu) { ax = fmaxf(ax, 0.f); ay = fmaxf(ay, 0.f); }
  if (ostride == TS) {
    *(float2*)(outp + (size_t)node * TS + c0) = make_float2(ax, ay);
  } else {
    float* o = outp + (size_t)node * ostride;
    if (c0 < D_H) o[c0] = ax;
    if (c1 < D_H) o[c1] = ay;
  }
}

// ---------- launch ----------
extern "C" void kernel_launch(void* const* d_in, const int* in_sizes, int n_in,
                              void* d_out, int out_size, void* d_ws, size_t ws_size,
                              hipStream_t stream) {
  const float* x  = (const float*)d_in[0];
  const void*  ei = d_in[1];
  const float* W1 = (const float*)d_in[2];
  const float* b1 = (const float*)d_in[3];
  const float* W2 = (const float*)d_in[4];
  const float* b2 = (const float*)d_in[5];
  int N = in_sizes[0] / D_IN;
  long long E = (long long)in_sizes[1] / 2;

  char* base = (char*)d_ws;
  size_t off = 0;
  auto alloc = [&](size_t bytes) -> void* {
    void* p = base + off;
    off = (off + bytes + 255) & ~(size_t)255;
    return p;
  };
  int*   flag      = (int*)alloc(4);
  int*   cnt       = (int*)alloc((size_t)N * 4);
  float* dinv      = (float*)alloc((size_t)N * 4);
  int*   row_start = (int*)alloc((size_t)(N + 1) * 4);
  int*   cursor    = (int*)alloc((size_t)N * 4);
  int*   bsum      = (int*)alloc(4096);
  int*   csr_src   = (int*)alloc((size_t)E * 4);
  float* W1p       = (float*)alloc((size_t)256 * WPAD * 4);
  float* W2p       = (float*)alloc((size_t)112 * WPAD * 4);
  float* b1p       = (float*)alloc(TS * 4);
  float* b2p       = (float*)alloc(TS * 4);
  float* t1        = (float*)alloc(((size_t)N * TS + 64) * 4);
  float* h1        = (float*)alloc(((size_t)N * TS + 64) * 4);

  hipMemsetAsync(cnt, 0, (size_t)N * 4, stream);
  detect_kernel<<<1, 256, 0, stream>>>(ei, E, flag);
  count_kernel<<<(int)((E + 255) / 256), 256, 0, stream>>>(ei, flag, cnt, E);
  dinv_kernel<<<(N + 255) / 256, 256, 0, stream>>>(cnt, dinv, N);
  int NB = (N + 1023) / 1024;
  scan_a<<<NB, 256, 0, stream>>>(cnt, bsum, N);
  scan_b<<<1, 1024, 0, stream>>>(bsum, NB);
  scan_c<<<NB, 256, 0, stream>>>(cnt, bsum, row_start, cursor, N, E);
  fill_kernel<<<(int)((E + 255) / 256), 256, 0, stream>>>(ei, flag, cursor, csr_src, E);
  prep_kernel<<<(256 * WPAD + 112 * WPAD + 2 * TS + 255) / 256, 256, 0, stream>>>(
      W1, b1, W2, b2, W1p, W2p, b1p, b2p);
  gemm_kernel<256, 256><<<(N + 63) / 64, 256, 0, stream>>>(x, D_IN, W1p, dinv, t1, N);
  agg_kernel<<<(N + 3) / 4, 256, 0, stream>>>(t1, csr_src, row_start, dinv, b1p, h1, N, TS, 1);
  gemm_kernel<112, 98><<<(N + 63) / 64, 256, 0, stream>>>(h1, TS, W2p, dinv, t1, N);
  agg_kernel<<<(N + 3) / 4, 256, 0, stream>>>(t1, csr_src, row_start, dinv, b2p,
                                              (float*)d_out, N, D_H, 0);
}

// Round 4
// 883.363 us; speedup vs baseline: 1.1011x; 1.1011x over previous
//
#include <hip/hip_runtime.h>
#include <hip/hip_bf16.h>
#include <stdint.h>

#define D_IN 256
#define D_H  97
#define TS   98      // padded row stride (floats) for t/h buffers; col 97 is a zero pad
#define WPAD 128     // padded weight column count
#define BSH  5       // bucket shift: 32 nodes per bucket
#define BMAX 4096    // max buckets supported (N <= 131072)

// ---------- helpers ----------
__device__ __forceinline__ int load_idx(const void* p, int is64, long long pos) {
  if (is64) return (int)(((const long long*)p)[pos]);
  return ((const int*)p)[pos];
}

// Decide whether edge_index arrived as int64 (odd 32-bit words all zero) or int32.
__global__ void detect_kernel(const void* ei, long long E, int* flag) {
  const int* p32 = (const int*)ei;
  long long stride = E / 1024; if (stride < 1) stride = 1;
  int tid = threadIdx.x;
  int bad = 0;
  for (int s = 0; s < 4; ++s) {
    long long k = ((long long)tid * 4 + s) * stride;
    if (k < E) {
      if (p32[2 * k + 1] != 0) bad = 1;
    }
  }
  __shared__ int sh_bad;
  if (tid == 0) sh_bad = 0;
  __syncthreads();
  if (bad) atomicOr(&sh_bad, 1);
  __syncthreads();
  if (tid == 0) *flag = sh_bad ? 0 : 1;   // 1 => int64
}

// ---------- bucketed CSR build ----------
// P1: per-bucket edge counts via LDS histogram
__global__ __launch_bounds__(256) void bucket_count(const void* ei, const int* __restrict__ flag,
                                                    int* __restrict__ bcnt, long long E, int nbuck) {
  __shared__ int h[BMAX];
  int tid = threadIdx.x;
  for (int i = tid; i < nbuck; i += 256) h[i] = 0;
  __syncthreads();
  int f = *flag;
  long long stride = (long long)gridDim.x * 256;
  for (long long e = (long long)blockIdx.x * 256 + tid; e < E; e += stride) {
    int d = load_idx(ei, f, E + e);
    atomicAdd(&h[d >> BSH], 1);
  }
  __syncthreads();
  for (int i = tid; i < nbuck; i += 256) { int v = h[i]; if (v) atomicAdd(&bcnt[i], v); }
}

// P2: exclusive scan of bucket counts (single WG, supports nbuck <= 4096)
__global__ void bucket_scan(const int* __restrict__ bcnt, int* __restrict__ bstart,
                            int* __restrict__ bcur, int nbuck) {
  __shared__ int sh[1024];
  int tid = threadIdx.x;
  int v[4]; int T = 0;
  #pragma unroll
  for (int k = 0; k < 4; ++k) {
    int idx = tid * 4 + k;
    v[k] = (idx < nbuck) ? bcnt[idx] : 0;
    T += v[k];
  }
  sh[tid] = T;
  __syncthreads();
  for (int off = 1; off < 1024; off <<= 1) {
    int a = (tid >= off) ? sh[tid - off] : 0;
    __syncthreads();
    sh[tid] += a;
    __syncthreads();
  }
  int run = sh[tid] - T;
  #pragma unroll
  for (int k = 0; k < 4; ++k) {
    int idx = tid * 4 + k;
    if (idx < nbuck) { bstart[idx] = run; bcur[idx] = run; }
    run += v[k];
  }
  if (tid == 1023) bstart[nbuck] = sh[1023];
}

// P3: scatter edges into contiguous per-bucket regions (append => spatially clustered writes)
__global__ __launch_bounds__(256) void bucket_scatter(const void* ei, const int* __restrict__ flag,
                                                      int* __restrict__ bcur, int2* __restrict__ bsd,
                                                      long long E) {
  long long e = (long long)blockIdx.x * blockDim.x + threadIdx.x;
  if (e >= E) return;
  int f = *flag;
  int s = load_idx(ei, f, e);
  int d = load_idx(ei, f, E + e);
  int pos = atomicAdd(&bcur[d >> BSH], 1);
  bsd[pos] = make_int2(s, d);
}

// P4: per-node degree from bucket data (non-atomic global write: node owned by one bucket)
__global__ __launch_bounds__(256) void bucket_nodecount(const int2* __restrict__ bsd,
                                                        const int* __restrict__ bstart,
                                                        int* __restrict__ cnt, int N) {
  int b = blockIdx.x, tid = threadIdx.x;
  __shared__ int h[32];
  if (tid < 32) h[tid] = 0;
  __syncthreads();
  int s0 = bstart[b], s1 = bstart[b + 1];
  for (int i = s0 + tid; i < s1; i += 256) atomicAdd(&h[bsd[i].y & 31], 1);
  __syncthreads();
  int node = b * 32 + tid;
  if (tid < 32 && node < N) cnt[node] = h[tid];
}

// P5: final CSR fill; LDS cursors, stores confined to bucket's contiguous CSR range
__global__ __launch_bounds__(256) void bucket_fill(const int2* __restrict__ bsd,
                                                   const int* __restrict__ bstart,
                                                   const int* __restrict__ row_start,
                                                   int* __restrict__ csr_src) {
  int b = blockIdx.x, tid = threadIdx.x;
  __shared__ int cur[32];
  if (tid < 32) cur[tid] = 0;
  __syncthreads();
  int s0 = bstart[b], s1 = bstart[b + 1];
  for (int i = s0 + tid; i < s1; i += 256) {
    int2 sd = bsd[i];
    int rel = atomicAdd(&cur[sd.y & 31], 1);
    csr_src[row_start[sd.y] + rel] = sd.x;
  }
}

__global__ void dinv_kernel(const int* __restrict__ cnt, float* __restrict__ dinv, int N) {
  int i = blockIdx.x * blockDim.x + threadIdx.x;
  if (i >= N) return;
  dinv[i] = rsqrtf((float)(cnt[i] + 1));   // +1 self-loop; deg >= 1 always
}

// ---------- exclusive scan over cnt -> row_start (3 phases) ----------
__global__ void scan_a(const int* __restrict__ cnt, int* __restrict__ bsum, int N) {
  int b = blockIdx.x, tid = threadIdx.x;
  int lane = tid & 63, wid = tid >> 6;
  int base = b * 1024 + tid * 4;
  int v0 = (base + 0 < N) ? cnt[base + 0] : 0;
  int v1 = (base + 1 < N) ? cnt[base + 1] : 0;
  int v2 = (base + 2 < N) ? cnt[base + 2] : 0;
  int v3 = (base + 3 < N) ? cnt[base + 3] : 0;
  int t = v0 + v1 + v2 + v3;
  #pragma unroll
  for (int off = 32; off > 0; off >>= 1) t += __shfl_down(t, off, 64);
  __shared__ int sh[4];
  if (lane == 0) sh[wid] = t;
  __syncthreads();
  if (tid == 0) bsum[b] = sh[0] + sh[1] + sh[2] + sh[3];
}

__global__ void scan_b(int* __restrict__ bsum, int NB) {
  __shared__ int sh[1024];
  int tid = threadIdx.x;
  int v = (tid < NB) ? bsum[tid] : 0;
  sh[tid] = v;
  __syncthreads();
  for (int off = 1; off < 1024; off <<= 1) {
    int a = (tid >= off) ? sh[tid - off] : 0;
    __syncthreads();
    sh[tid] += a;
    __syncthreads();
  }
  if (tid < NB) bsum[tid] = sh[tid] - v;   // exclusive block offsets
}

__global__ void scan_c(const int* __restrict__ cnt, const int* __restrict__ bsum,
                       int* __restrict__ row_start, int N, long long E_total) {
  int b = blockIdx.x, tid = threadIdx.x;
  int lane = tid & 63, wid = tid >> 6;
  int base = b * 1024 + tid * 4;
  int v0 = (base + 0 < N) ? cnt[base + 0] : 0;
  int v1 = (base + 1 < N) ? cnt[base + 1] : 0;
  int v2 = (base + 2 < N) ? cnt[base + 2] : 0;
  int v3 = (base + 3 < N) ? cnt[base + 3] : 0;
  int tsum = v0 + v1 + v2 + v3;
  int incl = tsum;
  #pragma unroll
  for (int off = 1; off < 64; off <<= 1) {
    int n = __shfl_up(incl, off, 64);
    if (lane >= off) incl += n;
  }
  __shared__ int wsum[4];
  if (lane == 63) wsum[wid] = incl;
  __syncthreads();
  int woff = 0;
  for (int k = 0; k < wid; ++k) woff += wsum[k];
  int excl = woff + incl - tsum + bsum[b];
  if (base + 0 < N) row_start[base + 0] = excl;
  if (base + 1 < N) row_start[base + 1] = excl + v0;
  if (base + 2 < N) row_start[base + 2] = excl + v0 + v1;
  if (base + 3 < N) row_start[base + 3] = excl + v0 + v1 + v2;
  if (b == 0 && tid == 0) row_start[N] = (int)E_total;
}

// ---------- pad weights/biases into WPAD-wide zero-padded buffers ----------
__global__ void prep_kernel(const float* __restrict__ W1, const float* __restrict__ b1,
                            const float* __restrict__ W2, const float* __restrict__ b2,
                            float* __restrict__ W1p, float* __restrict__ W2p,
                            float* __restrict__ b1p, float* __restrict__ b2p) {
  int idx = blockIdx.x * blockDim.x + threadIdx.x;
  const int n1 = 256 * WPAD, n2 = 112 * WPAD;
  if (idx < n1) {
    int k = idx / WPAD, c = idx % WPAD;
    W1p[idx] = (c < D_H) ? W1[k * D_H + c] : 0.0f;
  } else if (idx < n1 + n2) {
    int j = idx - n1; int k = j / WPAD, c = j % WPAD;
    W2p[j] = (k < D_H && c < D_H) ? W2[k * D_H + c] : 0.0f;
  } else if (idx < n1 + n2 + TS) {
    int c = idx - (n1 + n2);
    b1p[c] = (c < D_H) ? b1[c] : 0.0f;
  } else if (idx < n1 + n2 + 2 * TS) {
    int c = idx - (n1 + n2 + TS);
    b2p[c] = (c < D_H) ? b2[c] : 0.0f;
  }
}

// ---------- f32 tiled GEMM: C[N x TS(pad)] = (A[N x lda] * Wp[K x WPAD]) * dinv[row] ----------
template<int K, int KEFF>
__global__ __launch_bounds__(256) void gemm_kernel(const float* __restrict__ A, int lda,
                                                   const float* __restrict__ Wp,
                                                   const float* __restrict__ dinv,
                                                   float* __restrict__ C, int N) {
  __shared__ float As[16][64];
  __shared__ float Ws[16][128];
  int tid = threadIdx.x;
  int row0 = blockIdx.x * 64;
  int tx = tid & 15, ty = tid >> 4;
  float acc[4][8];
  #pragma unroll
  for (int i = 0; i < 4; ++i)
    #pragma unroll
    for (int j = 0; j < 8; ++j) acc[i][j] = 0.0f;

  int ar  = tid >> 2;          // 0..63 row within tile
  int akq = (tid & 3) * 4;     // k offset 0,4,8,12
  int wc  = (tid & 31) * 4;    // 0..124
  int wk  = tid >> 5;          // 0..7

  for (int kb = 0; kb < K; kb += 16) {
    float2 a01 = make_float2(0.f, 0.f), a23 = make_float2(0.f, 0.f);
    int arow = row0 + ar;
    int k0 = kb + akq;
    if (arow < N) {
      if (k0 < KEFF)     a01 = *(const float2*)&A[(size_t)arow * lda + k0];
      if (k0 + 2 < KEFF) a23 = *(const float2*)&A[(size_t)arow * lda + k0 + 2];
    }
    As[akq + 0][ar] = a01.x; As[akq + 1][ar] = a01.y;
    As[akq + 2][ar] = a23.x; As[akq + 3][ar] = a23.y;
    *(float4*)&Ws[wk][wc]     = *(const float4*)&Wp[(size_t)(kb + wk) * WPAD + wc];
    *(float4*)&Ws[wk + 8][wc] = *(const float4*)&Wp[(size_t)(kb + wk + 8) * WPAD + wc];
    __syncthreads();
    #pragma unroll
    for (int k = 0; k < 16; ++k) {
      float4 a4 = *(const float4*)&As[k][ty * 4];
      float4 wA = *(const float4*)&Ws[k][tx * 4];
      float4 wB = *(const float4*)&Ws[k][64 + tx * 4];
      float av[4] = {a4.x, a4.y, a4.z, a4.w};
      float wv[8] = {wA.x, wA.y, wA.z, wA.w, wB.x, wB.y, wB.z, wB.w};
      #pragma unroll
      for (int i = 0; i < 4; ++i)
        #pragma unroll
        for (int j = 0; j < 8; ++j) acc[i][j] += av[i] * wv[j];
    }
    __syncthreads();
  }
  #pragma unroll
  for (int i = 0; i < 4; ++i) {
    int r = row0 + ty * 4 + i;
    if (r >= N) continue;
    float dv = dinv[r];
    float* crow = C + (size_t)r * TS;
    int cA = tx * 4, cB = 64 + tx * 4;
    *(float2*)&crow[cA]     = make_float2(acc[i][0] * dv, acc[i][1] * dv);
    *(float2*)&crow[cA + 2] = make_float2(acc[i][2] * dv, acc[i][3] * dv);
    if (cB < TS)     *(float2*)&crow[cB]     = make_float2(acc[i][4] * dv, acc[i][5] * dv);
    if (cB + 2 < TS) *(float2*)&crow[cB + 2] = make_float2(acc[i][6] * dv, acc[i][7] * dv);
  }
}

// ---------- CSR aggregation: one wave per destination node, pure row-sum ----------
// t rows are pre-scaled by dinv[src]; final scale by dinv[node] here.
__global__ __launch_bounds__(256) void agg_kernel(
    const float* __restrict__ t, const int* __restrict__ csr_src,
    const int* __restrict__ row_start,
    const float* __restrict__ dinv, const float* __restrict__ bias,
    float* __restrict__ outp, int N, int ostride, int do_relu) {
  int lane = threadIdx.x & 63;
  int node = blockIdx.x * (blockDim.x >> 6) + (threadIdx.x >> 6);
  if (node >= N || lane >= 49) return;   // 49 lanes x float2 = 98 cols (col 97 is zero pad)
  int s = row_start[node], epd = row_start[node + 1];
  float di = dinv[node];
  float2 v = ((const float2*)(t + (size_t)node * TS))[lane];  // self term (already ×dinv[node])
  float ax = v.x, ay = v.y;
  int e = s;
  for (; e + 4 <= epd; e += 4) {
    int j0 = csr_src[e], j1 = csr_src[e + 1], j2 = csr_src[e + 2], j3 = csr_src[e + 3];
    float2 u0 = ((const float2*)(t + (size_t)j0 * TS))[lane];
    float2 u1 = ((const float2*)(t + (size_t)j1 * TS))[lane];
    float2 u2 = ((const float2*)(t + (size_t)j2 * TS))[lane];
    float2 u3 = ((const float2*)(t + (size_t)j3 * TS))[lane];
    ax += u0.x; ay += u0.y;
    ax += u1.x; ay += u1.y;
    ax += u2.x; ay += u2.y;
    ax += u3.x; ay += u3.y;
  }
  for (; e < epd; ++e) {
    int j = csr_src[e];
    float2 u = ((const float2*)(t + (size_t)j * TS))[lane];
    ax += u.x; ay += u.y;
  }
  int c0 = 2 * lane, c1 = 2 * lane + 1;
  ax = ax * di + bias[c0];
  ay = ay * di + bias[c1];
  if (do_relu) { ax = fmaxf(ax, 0.f); ay = fmaxf(ay, 0.f); }
  if (ostride == TS) {
    *(float2*)(outp + (size_t)node * TS + c0) = make_float2(ax, ay);
  } else {
    float* o = outp + (size_t)node * ostride;
    if (c0 < D_H) o[c0] = ax;
    if (c1 < D_H) o[c1] = ay;
  }
}

// ---------- launch ----------
extern "C" void kernel_launch(void* const* d_in, const int* in_sizes, int n_in,
                              void* d_out, int out_size, void* d_ws, size_t ws_size,
                              hipStream_t stream) {
  const float* x  = (const float*)d_in[0];
  const void*  ei = d_in[1];
  const float* W1 = (const float*)d_in[2];
  const float* b1 = (const float*)d_in[3];
  const float* W2 = (const float*)d_in[4];
  const float* b2 = (const float*)d_in[5];
  int N = in_sizes[0] / D_IN;
  long long E = (long long)in_sizes[1] / 2;
  int nbuck = (N + 31) >> BSH;

  char* base = (char*)d_ws;
  size_t off = 0;
  auto alloc = [&](size_t bytes) -> void* {
    void* p = base + off;
    off = (off + bytes + 255) & ~(size_t)255;
    return p;
  };
  int*   flag      = (int*)alloc(4);
  int*   cnt       = (int*)alloc((size_t)N * 4);
  float* dinv      = (float*)alloc((size_t)N * 4);
  int*   row_start = (int*)alloc((size_t)(N + 1) * 4);
  int*   bsum      = (int*)alloc(4096);
  int*   bcnt      = (int*)alloc((size_t)(nbuck + 1) * 4);
  int*   bstart    = (int*)alloc((size_t)(nbuck + 1) * 4);
  int*   bcur      = (int*)alloc((size_t)(nbuck + 1) * 4);
  int*   csr_src   = (int*)alloc((size_t)E * 4);
  float* W1p       = (float*)alloc((size_t)256 * WPAD * 4);
  float* W2p       = (float*)alloc((size_t)112 * WPAD * 4);
  float* b1p       = (float*)alloc(TS * 4);
  float* b2p       = (float*)alloc(TS * 4);
  float* t1        = (float*)alloc(((size_t)N * TS + 64) * 4);
  float* h1        = (float*)alloc(((size_t)N * TS + 64) * 4);
  int2*  bsd       = (int2*)t1;   // aliases t1: bsd dead before gemm1 writes t1

  hipMemsetAsync(bcnt, 0, (size_t)(nbuck + 1) * 4, stream);
  detect_kernel<<<1, 256, 0, stream>>>(ei, E, flag);
  bucket_count<<<256, 256, 0, stream>>>(ei, flag, bcnt, E, nbuck);
  bucket_scan<<<1, 1024, 0, stream>>>(bcnt, bstart, bcur, nbuck);
  bucket_scatter<<<(int)((E + 255) / 256), 256, 0, stream>>>(ei, flag, bcur, bsd, E);
  bucket_nodecount<<<nbuck, 256, 0, stream>>>(bsd, bstart, cnt, N);
  dinv_kernel<<<(N + 255) / 256, 256, 0, stream>>>(cnt, dinv, N);
  int NB = (N + 1023) / 1024;
  scan_a<<<NB, 256, 0, stream>>>(cnt, bsum, N);
  scan_b<<<1, 1024, 0, stream>>>(bsum, NB);
  scan_c<<<NB, 256, 0, stream>>>(cnt, bsum, row_start, N, E);
  bucket_fill<<<nbuck, 256, 0, stream>>>(bsd, bstart, row_start, csr_src);
  prep_kernel<<<(256 * WPAD + 112 * WPAD + 2 * TS + 255) / 256, 256, 0, stream>>>(
      W1, b1, W2, b2, W1p, W2p, b1p, b2p);
  gemm_kernel<256, 256><<<(N + 63) / 64, 256, 0, stream>>>(x, D_IN, W1p, dinv, t1, N);
  agg_kernel<<<(N + 3) / 4, 256, 0, stream>>>(t1, csr_src, row_start, dinv, b1p, h1, N, TS, 1);
  gemm_kernel<112, 98><<<(N + 63) / 64, 256, 0, stream>>>(h1, TS, W2p, dinv, t1, N);
  agg_kernel<<<(N + 3) / 4, 256, 0, stream>>>(t1, csr_src, row_start, dinv, b2p,
                                              (float*)d_out, N, D_H, 0);
}

// Round 5
// 658.477 us; speedup vs baseline: 1.4771x; 1.3415x over previous
//
#include <hip/hip_runtime.h>
#include <hip/hip_bf16.h>
#include <stdint.h>

#define D_IN 256
#define D_H  97
#define TS   98      // padded row stride (floats) for t/h buffers; col 97 is a zero pad
#define WPAD 128     // padded weight column count
#define NPB  512     // nodes per coarse bucket (shift 9); supports N <= 131072 (src packs in 17 bits)
#define NBMAX 256    // max coarse buckets
#define CHUNK 4096   // edges per scatter WG

// ---------- helpers ----------
__device__ __forceinline__ int load_idx(const void* p, int is64, long long pos) {
  if (is64) return (int)(((const long long*)p)[pos]);
  return ((const int*)p)[pos];
}

// Decide whether edge_index arrived as int64 (odd 32-bit words all zero) or int32.
__global__ void detect_kernel(const void* ei, long long E, int* flag) {
  const int* p32 = (const int*)ei;
  long long stride = E / 1024; if (stride < 1) stride = 1;
  int tid = threadIdx.x;
  int bad = 0;
  for (int s = 0; s < 4; ++s) {
    long long k = ((long long)tid * 4 + s) * stride;
    if (k < E) {
      if (p32[2 * k + 1] != 0) bad = 1;
    }
  }
  __shared__ int sh_bad;
  if (tid == 0) sh_bad = 0;
  __syncthreads();
  if (bad) atomicOr(&sh_bad, 1);
  __syncthreads();
  if (tid == 0) *flag = sh_bad ? 0 : 1;   // 1 => int64
}

// P1: per-coarse-bucket edge counts via LDS histogram
__global__ __launch_bounds__(256) void bucket_count(const void* ei, const int* __restrict__ flag,
                                                    int* __restrict__ bcnt, long long E, int nbuck) {
  __shared__ int h[NBMAX];
  int tid = threadIdx.x;
  if (tid < NBMAX) h[tid] = 0;
  __syncthreads();
  int f = *flag;
  long long stride = (long long)gridDim.x * 256;
  for (long long e = (long long)blockIdx.x * 256 + tid; e < E; e += stride) {
    int d = load_idx(ei, f, E + e);
    atomicAdd(&h[d >> 9], 1);
  }
  __syncthreads();
  if (tid < nbuck) { int v = h[tid]; if (v) atomicAdd(&bcnt[tid], v); }
}

// P2: exclusive scan of bucket counts (single WG of 256)
__global__ void bucket_scan(const int* __restrict__ bcnt, int* __restrict__ bstart,
                            int* __restrict__ bcur, int nbuck) {
  __shared__ int sh[256];
  int tid = threadIdx.x;
  int v = (tid < nbuck) ? bcnt[tid] : 0;
  sh[tid] = v;
  __syncthreads();
  for (int off = 1; off < 256; off <<= 1) {
    int a = (tid >= off) ? sh[tid - off] : 0;
    __syncthreads();
    sh[tid] += a;
    __syncthreads();
  }
  int excl = sh[tid] - v;
  if (tid < nbuck) { bstart[tid] = excl; bcur[tid] = excl; }
  if (tid == 255) bstart[nbuck] = sh[255];
}

// P3: chunked scatter with per-chunk bulk allocation.
// One global atomic per (chunk,bucket); each WG then owns a contiguous sub-range
// of each bucket => writes are spatially clustered, no cross-WG line sharing.
__global__ __launch_bounds__(256) void bucket_scatter_staged(
    const void* ei, const int* __restrict__ flag, int* __restrict__ bcur,
    unsigned int* __restrict__ bsd, long long E, int nbuck) {
  __shared__ unsigned int packs[CHUNK];
  __shared__ unsigned char bkts[CHUNK];
  __shared__ int hist[NBMAX];
  __shared__ int gpos[NBMAX];
  __shared__ int cur[NBMAX];
  int tid = threadIdx.x;
  if (tid < NBMAX) { hist[tid] = 0; cur[tid] = 0; }
  __syncthreads();
  int f = *flag;
  long long base = (long long)blockIdx.x * CHUNK;
  int cnt = (int)((E - base < CHUNK) ? (E - base) : CHUNK);
  #pragma unroll 4
  for (int i = tid; i < cnt; i += 256) {
    long long e = base + i;
    int s = load_idx(ei, f, e);
    int d = load_idx(ei, f, E + e);
    int b = d >> 9;
    packs[i] = ((unsigned int)(d & (NPB - 1)) << 17) | (unsigned int)s;
    bkts[i] = (unsigned char)b;
    atomicAdd(&hist[b], 1);
  }
  __syncthreads();
  if (tid < nbuck) { int h = hist[tid]; if (h) gpos[tid] = atomicAdd(&bcur[tid], h); }
  __syncthreads();
  #pragma unroll 4
  for (int i = tid; i < cnt; i += 256) {
    int b = bkts[i];
    int r = atomicAdd(&cur[b], 1);
    bsd[gpos[b] + r] = packs[i];
  }
}

// P4: per-bucket finalize: node histogram -> prefix -> row_start + dinv -> CSR scatter.
// All scattered stores confined to this bucket's ~hist*4B CSR window (L2-absorbed).
__global__ __launch_bounds__(256) void bucket_finalize(
    const unsigned int* __restrict__ bsd, const int* __restrict__ bstart,
    int* __restrict__ row_start, float* __restrict__ dinv,
    int* __restrict__ csr_src, int N, long long E, int nbuck) {
  __shared__ int h[NPB];
  __shared__ int rs[NPB];     // absolute global CSR base per local node
  __shared__ int cur[NPB];
  __shared__ int wsum[4];
  int b = blockIdx.x, tid = threadIdx.x;
  int lane = tid & 63, wid = tid >> 6;
  h[2 * tid] = 0; h[2 * tid + 1] = 0;
  cur[2 * tid] = 0; cur[2 * tid + 1] = 0;
  __syncthreads();
  int s0 = bstart[b], s1 = bstart[b + 1];
  for (int i = s0 + tid; i < s1; i += 256) atomicAdd(&h[bsd[i] >> 17], 1);
  __syncthreads();
  // exclusive prefix over 512 entries (2 per thread)
  int a0 = h[2 * tid], a1 = h[2 * tid + 1];
  int tsum = a0 + a1;
  int incl = tsum;
  #pragma unroll
  for (int off = 1; off < 64; off <<= 1) {
    int n = __shfl_up(incl, off, 64);
    if (lane >= off) incl += n;
  }
  if (lane == 63) wsum[wid] = incl;
  __syncthreads();
  int woff = 0;
  for (int k = 0; k < wid; ++k) woff += wsum[k];
  int excl = woff + incl - tsum + s0;
  rs[2 * tid] = excl;
  rs[2 * tid + 1] = excl + a0;
  int node0 = b * NPB;
  int n0 = node0 + 2 * tid, n1 = node0 + 2 * tid + 1;
  if (n0 < N) { row_start[n0] = excl;      dinv[n0] = rsqrtf((float)(a0 + 1)); }
  if (n1 < N) { row_start[n1] = excl + a0; dinv[n1] = rsqrtf((float)(a1 + 1)); }
  if (b == nbuck - 1 && tid == 0) row_start[N] = (int)E;
  __syncthreads();
  for (int i = s0 + tid; i < s1; i += 256) {
    unsigned int p = bsd[i];
    int r = p >> 17;
    int s = (int)(p & 0x1FFFFu);
    int rel = atomicAdd(&cur[r], 1);
    csr_src[rs[r] + rel] = s;
  }
}

// ---------- pad weights/biases into WPAD-wide zero-padded buffers ----------
__global__ void prep_kernel(const float* __restrict__ W1, const float* __restrict__ b1,
                            const float* __restrict__ W2, const float* __restrict__ b2,
                            float* __restrict__ W1p, float* __restrict__ W2p,
                            float* __restrict__ b1p, float* __restrict__ b2p) {
  int idx = blockIdx.x * blockDim.x + threadIdx.x;
  const int n1 = 256 * WPAD, n2 = 112 * WPAD;
  if (idx < n1) {
    int k = idx / WPAD, c = idx % WPAD;
    W1p[idx] = (c < D_H) ? W1[k * D_H + c] : 0.0f;
  } else if (idx < n1 + n2) {
    int j = idx - n1; int k = j / WPAD, c = j % WPAD;
    W2p[j] = (k < D_H && c < D_H) ? W2[k * D_H + c] : 0.0f;
  } else if (idx < n1 + n2 + TS) {
    int c = idx - (n1 + n2);
    b1p[c] = (c < D_H) ? b1[c] : 0.0f;
  } else if (idx < n1 + n2 + 2 * TS) {
    int c = idx - (n1 + n2 + TS);
    b2p[c] = (c < D_H) ? b2[c] : 0.0f;
  }
}

// ---------- f32 tiled GEMM: C[N x TS(pad)] = (A[N x lda] * Wp[K x WPAD]) * dinv[row] ----------
template<int K, int KEFF>
__global__ __launch_bounds__(256) void gemm_kernel(const float* __restrict__ A, int lda,
                                                   const float* __restrict__ Wp,
                                                   const float* __restrict__ dinv,
                                                   float* __restrict__ C, int N) {
  __shared__ float As[16][64];
  __shared__ float Ws[16][128];
  int tid = threadIdx.x;
  int row0 = blockIdx.x * 64;
  int tx = tid & 15, ty = tid >> 4;
  float acc[4][8];
  #pragma unroll
  for (int i = 0; i < 4; ++i)
    #pragma unroll
    for (int j = 0; j < 8; ++j) acc[i][j] = 0.0f;

  int ar  = tid >> 2;          // 0..63 row within tile
  int akq = (tid & 3) * 4;     // k offset 0,4,8,12
  int wc  = (tid & 31) * 4;    // 0..124
  int wk  = tid >> 5;          // 0..7

  for (int kb = 0; kb < K; kb += 16) {
    float2 a01 = make_float2(0.f, 0.f), a23 = make_float2(0.f, 0.f);
    int arow = row0 + ar;
    int k0 = kb + akq;
    if (arow < N) {
      if (k0 < KEFF)     a01 = *(const float2*)&A[(size_t)arow * lda + k0];
      if (k0 + 2 < KEFF) a23 = *(const float2*)&A[(size_t)arow * lda + k0 + 2];
    }
    As[akq + 0][ar] = a01.x; As[akq + 1][ar] = a01.y;
    As[akq + 2][ar] = a23.x; As[akq + 3][ar] = a23.y;
    *(float4*)&Ws[wk][wc]     = *(const float4*)&Wp[(size_t)(kb + wk) * WPAD + wc];
    *(float4*)&Ws[wk + 8][wc] = *(const float4*)&Wp[(size_t)(kb + wk + 8) * WPAD + wc];
    __syncthreads();
    #pragma unroll
    for (int k = 0; k < 16; ++k) {
      float4 a4 = *(const float4*)&As[k][ty * 4];
      float4 wA = *(const float4*)&Ws[k][tx * 4];
      float4 wB = *(const float4*)&Ws[k][64 + tx * 4];
      float av[4] = {a4.x, a4.y, a4.z, a4.w};
      float wv[8] = {wA.x, wA.y, wA.z, wA.w, wB.x, wB.y, wB.z, wB.w};
      #pragma unroll
      for (int i = 0; i < 4; ++i)
        #pragma unroll
        for (int j = 0; j < 8; ++j) acc[i][j] += av[i] * wv[j];
    }
    __syncthreads();
  }
  #pragma unroll
  for (int i = 0; i < 4; ++i) {
    int r = row0 + ty * 4 + i;
    if (r >= N) continue;
    float dv = dinv[r];
    float* crow = C + (size_t)r * TS;
    int cA = tx * 4, cB = 64 + tx * 4;
    *(float2*)&crow[cA]     = make_float2(acc[i][0] * dv, acc[i][1] * dv);
    *(float2*)&crow[cA + 2] = make_float2(acc[i][2] * dv, acc[i][3] * dv);
    if (cB < TS)     *(float2*)&crow[cB]     = make_float2(acc[i][4] * dv, acc[i][5] * dv);
    if (cB + 2 < TS) *(float2*)&crow[cB + 2] = make_float2(acc[i][6] * dv, acc[i][7] * dv);
  }
}

// ---------- CSR aggregation: one wave per destination node, pure row-sum ----------
// t rows are pre-scaled by dinv[src]; final scale by dinv[node] here.
__global__ __launch_bounds__(256) void agg_kernel(
    const float* __restrict__ t, const int* __restrict__ csr_src,
    const int* __restrict__ row_start,
    const float* __restrict__ dinv, const float* __restrict__ bias,
    float* __restrict__ outp, int N, int ostride, int do_relu) {
  int lane = threadIdx.x & 63;
  int node = blockIdx.x * (blockDim.x >> 6) + (threadIdx.x >> 6);
  if (node >= N || lane >= 49) return;   // 49 lanes x float2 = 98 cols (col 97 is zero pad)
  int s = row_start[node], epd = row_start[node + 1];
  float di = dinv[node];
  float2 v = ((const float2*)(t + (size_t)node * TS))[lane];  // self term (already ×dinv[node])
  float ax = v.x, ay = v.y;
  int e = s;
  for (; e + 4 <= epd; e += 4) {
    int j0 = csr_src[e], j1 = csr_src[e + 1], j2 = csr_src[e + 2], j3 = csr_src[e + 3];
    float2 u0 = ((const float2*)(t + (size_t)j0 * TS))[lane];
    float2 u1 = ((const float2*)(t + (size_t)j1 * TS))[lane];
    float2 u2 = ((const float2*)(t + (size_t)j2 * TS))[lane];
    float2 u3 = ((const float2*)(t + (size_t)j3 * TS))[lane];
    ax += u0.x; ay += u0.y;
    ax += u1.x; ay += u1.y;
    ax += u2.x; ay += u2.y;
    ax += u3.x; ay += u3.y;
  }
  for (; e < epd; ++e) {
    int j = csr_src[e];
    float2 u = ((const float2*)(t + (size_t)j * TS))[lane];
    ax += u.x; ay += u.y;
  }
  int c0 = 2 * lane, c1 = 2 * lane + 1;
  ax = ax * di + bias[c0];
  ay = ay * di + bias[c1];
  if (do_relu) { ax = fmaxf(ax, 0.f); ay = fmaxf(ay, 0.f); }
  if (ostride == TS) {
    *(float2*)(outp + (size_t)node * TS + c0) = make_float2(ax, ay);
  } else {
    float* o = outp + (size_t)node * ostride;
    if (c0 < D_H) o[c0] = ax;
    if (c1 < D_H) o[c1] = ay;
  }
}

// ---------- launch ----------
extern "C" void kernel_launch(void* const* d_in, const int* in_sizes, int n_in,
                              void* d_out, int out_size, void* d_ws, size_t ws_size,
                              hipStream_t stream) {
  const float* x  = (const float*)d_in[0];
  const void*  ei = d_in[1];
  const float* W1 = (const float*)d_in[2];
  const float* b1 = (const float*)d_in[3];
  const float* W2 = (const float*)d_in[4];
  const float* b2 = (const float*)d_in[5];
  int N = in_sizes[0] / D_IN;
  long long E = (long long)in_sizes[1] / 2;
  int nbuck = (N + NPB - 1) / NPB;

  char* base = (char*)d_ws;
  size_t off = 0;
  auto alloc = [&](size_t bytes) -> void* {
    void* p = base + off;
    off = (off + bytes + 255) & ~(size_t)255;
    return p;
  };
  int*   flag      = (int*)alloc(4);
  float* dinv      = (float*)alloc((size_t)N * 4);
  int*   row_start = (int*)alloc((size_t)(N + 1) * 4);
  int*   bcnt      = (int*)alloc((size_t)(nbuck + 1) * 4);
  int*   bstart    = (int*)alloc((size_t)(nbuck + 1) * 4);
  int*   bcur      = (int*)alloc((size_t)(nbuck + 1) * 4);
  int*   csr_src   = (int*)alloc((size_t)E * 4);
  float* W1p       = (float*)alloc((size_t)256 * WPAD * 4);
  float* W2p       = (float*)alloc((size_t)112 * WPAD * 4);
  float* b1p       = (float*)alloc(TS * 4);
  float* b2p       = (float*)alloc(TS * 4);
  float* t1        = (float*)alloc(((size_t)N * TS + 64) * 4);
  float* h1        = (float*)alloc(((size_t)N * TS + 64) * 4);
  unsigned int* bsd = (unsigned int*)t1;   // aliases t1: bsd dead before gemm1 writes t1

  hipMemsetAsync(bcnt, 0, (size_t)(nbuck + 1) * 4, stream);
  detect_kernel<<<1, 256, 0, stream>>>(ei, E, flag);
  bucket_count<<<256, 256, 0, stream>>>(ei, flag, bcnt, E, nbuck);
  bucket_scan<<<1, 256, 0, stream>>>(bcnt, bstart, bcur, nbuck);
  bucket_scatter_staged<<<(int)((E + CHUNK - 1) / CHUNK), 256, 0, stream>>>(
      ei, flag, bcur, bsd, E, nbuck);
  bucket_finalize<<<nbuck, 256, 0, stream>>>(bsd, bstart, row_start, dinv, csr_src, N, E, nbuck);
  prep_kernel<<<(256 * WPAD + 112 * WPAD + 2 * TS + 255) / 256, 256, 0, stream>>>(
      W1, b1, W2, b2, W1p, W2p, b1p, b2p);
  gemm_kernel<256, 256><<<(N + 63) / 64, 256, 0, stream>>>(x, D_IN, W1p, dinv, t1, N);
  agg_kernel<<<(N + 3) / 4, 256, 0, stream>>>(t1, csr_src, row_start, dinv, b1p, h1, N, TS, 1);
  gemm_kernel<112, 98><<<(N + 63) / 64, 256, 0, stream>>>(h1, TS, W2p, dinv, t1, N);
  agg_kernel<<<(N + 3) / 4, 256, 0, stream>>>(t1, csr_src, row_start, dinv, b2p,
                                              (float*)d_out, N, D_H, 0);
}

// Round 6
// 481.805 us; speedup vs baseline: 2.0187x; 1.3667x over previous
//
#include <hip/hip_runtime.h>
#include <hip/hip_bf16.h>
#include <hip/hip_fp16.h>
#include <stdint.h>

#define D_IN 256
#define D_H  97
#define TSH  128     // half-precision row stride for t/h buffers (256 B, 4 cache lines, aligned)
#define WPAD 128     // padded weight column count
#define NPB  512     // nodes per coarse bucket (shift 9); supports N <= 131072 (src packs in 17 bits)
#define NBMAX 256    // max coarse buckets
#define CHUNK 4096   // edges per scatter WG

// ---------- helpers ----------
__device__ __forceinline__ int load_idx(const void* p, int is64, long long pos) {
  if (is64) return (int)(((const long long*)p)[pos]);
  return ((const int*)p)[pos];
}

// Decide whether edge_index arrived as int64 (odd 32-bit words all zero) or int32.
__global__ void detect_kernel(const void* ei, long long E, int* flag) {
  const int* p32 = (const int*)ei;
  long long stride = E / 1024; if (stride < 1) stride = 1;
  int tid = threadIdx.x;
  int bad = 0;
  for (int s = 0; s < 4; ++s) {
    long long k = ((long long)tid * 4 + s) * stride;
    if (k < E) {
      if (p32[2 * k + 1] != 0) bad = 1;
    }
  }
  __shared__ int sh_bad;
  if (tid == 0) sh_bad = 0;
  __syncthreads();
  if (bad) atomicOr(&sh_bad, 1);
  __syncthreads();
  if (tid == 0) *flag = sh_bad ? 0 : 1;   // 1 => int64
}

// P1: per-coarse-bucket edge counts via LDS histogram
__global__ __launch_bounds__(256) void bucket_count(const void* ei, const int* __restrict__ flag,
                                                    int* __restrict__ bcnt, long long E, int nbuck) {
  __shared__ int h[NBMAX];
  int tid = threadIdx.x;
  if (tid < NBMAX) h[tid] = 0;
  __syncthreads();
  int f = *flag;
  long long stride = (long long)gridDim.x * 256;
  for (long long e = (long long)blockIdx.x * 256 + tid; e < E; e += stride) {
    int d = load_idx(ei, f, E + e);
    atomicAdd(&h[d >> 9], 1);
  }
  __syncthreads();
  if (tid < nbuck) { int v = h[tid]; if (v) atomicAdd(&bcnt[tid], v); }
}

// P2: exclusive scan of bucket counts (single WG of 256)
__global__ void bucket_scan(const int* __restrict__ bcnt, int* __restrict__ bstart,
                            int* __restrict__ bcur, int nbuck) {
  __shared__ int sh[256];
  int tid = threadIdx.x;
  int v = (tid < nbuck) ? bcnt[tid] : 0;
  sh[tid] = v;
  __syncthreads();
  for (int off = 1; off < 256; off <<= 1) {
    int a = (tid >= off) ? sh[tid - off] : 0;
    __syncthreads();
    sh[tid] += a;
    __syncthreads();
  }
  int excl = sh[tid] - v;
  if (tid < nbuck) { bstart[tid] = excl; bcur[tid] = excl; }
  if (tid == 255) bstart[nbuck] = sh[255];
}

// P3: chunked scatter with per-chunk bulk allocation.
__global__ __launch_bounds__(256) void bucket_scatter_staged(
    const void* ei, const int* __restrict__ flag, int* __restrict__ bcur,
    unsigned int* __restrict__ bsd, long long E, int nbuck) {
  __shared__ unsigned int packs[CHUNK];
  __shared__ unsigned char bkts[CHUNK];
  __shared__ int hist[NBMAX];
  __shared__ int gpos[NBMAX];
  __shared__ int cur[NBMAX];
  int tid = threadIdx.x;
  if (tid < NBMAX) { hist[tid] = 0; cur[tid] = 0; }
  __syncthreads();
  int f = *flag;
  long long base = (long long)blockIdx.x * CHUNK;
  int cnt = (int)((E - base < CHUNK) ? (E - base) : CHUNK);
  #pragma unroll 4
  for (int i = tid; i < cnt; i += 256) {
    long long e = base + i;
    int s = load_idx(ei, f, e);
    int d = load_idx(ei, f, E + e);
    int b = d >> 9;
    packs[i] = ((unsigned int)(d & (NPB - 1)) << 17) | (unsigned int)s;
    bkts[i] = (unsigned char)b;
    atomicAdd(&hist[b], 1);
  }
  __syncthreads();
  if (tid < nbuck) { int h = hist[tid]; if (h) gpos[tid] = atomicAdd(&bcur[tid], h); }
  __syncthreads();
  #pragma unroll 4
  for (int i = tid; i < cnt; i += 256) {
    int b = bkts[i];
    int r = atomicAdd(&cur[b], 1);
    bsd[gpos[b] + r] = packs[i];
  }
}

// P4: per-bucket finalize: node histogram -> prefix -> row_start + dinv -> CSR scatter.
__global__ __launch_bounds__(256) void bucket_finalize(
    const unsigned int* __restrict__ bsd, const int* __restrict__ bstart,
    int* __restrict__ row_start, float* __restrict__ dinv,
    int* __restrict__ csr_src, int N, long long E, int nbuck) {
  __shared__ int h[NPB];
  __shared__ int rs[NPB];
  __shared__ int cur[NPB];
  __shared__ int wsum[4];
  int b = blockIdx.x, tid = threadIdx.x;
  int lane = tid & 63, wid = tid >> 6;
  h[2 * tid] = 0; h[2 * tid + 1] = 0;
  cur[2 * tid] = 0; cur[2 * tid + 1] = 0;
  __syncthreads();
  int s0 = bstart[b], s1 = bstart[b + 1];
  for (int i = s0 + tid; i < s1; i += 256) atomicAdd(&h[bsd[i] >> 17], 1);
  __syncthreads();
  int a0 = h[2 * tid], a1 = h[2 * tid + 1];
  int tsum = a0 + a1;
  int incl = tsum;
  #pragma unroll
  for (int off = 1; off < 64; off <<= 1) {
    int n = __shfl_up(incl, off, 64);
    if (lane >= off) incl += n;
  }
  if (lane == 63) wsum[wid] = incl;
  __syncthreads();
  int woff = 0;
  for (int k = 0; k < wid; ++k) woff += wsum[k];
  int excl = woff + incl - tsum + s0;
  rs[2 * tid] = excl;
  rs[2 * tid + 1] = excl + a0;
  int node0 = b * NPB;
  int n0 = node0 + 2 * tid, n1 = node0 + 2 * tid + 1;
  if (n0 < N) { row_start[n0] = excl;      dinv[n0] = rsqrtf((float)(a0 + 1)); }
  if (n1 < N) { row_start[n1] = excl + a0; dinv[n1] = rsqrtf((float)(a1 + 1)); }
  if (b == nbuck - 1 && tid == 0) row_start[N] = (int)E;
  __syncthreads();
  for (int i = s0 + tid; i < s1; i += 256) {
    unsigned int p = bsd[i];
    int r = p >> 17;
    int s = (int)(p & 0x1FFFFu);
    int rel = atomicAdd(&cur[r], 1);
    csr_src[rs[r] + rel] = s;
  }
}

// ---------- pad weights/biases into WPAD-wide zero-padded buffers ----------
__global__ void prep_kernel(const float* __restrict__ W1, const float* __restrict__ b1,
                            const float* __restrict__ W2, const float* __restrict__ b2,
                            float* __restrict__ W1p, float* __restrict__ W2p,
                            float* __restrict__ b1p, float* __restrict__ b2p) {
  int idx = blockIdx.x * blockDim.x + threadIdx.x;
  const int n1 = 256 * WPAD, n2 = 112 * WPAD;
  if (idx < n1) {
    int k = idx / WPAD, c = idx % WPAD;
    W1p[idx] = (c < D_H) ? W1[k * D_H + c] : 0.0f;
  } else if (idx < n1 + n2) {
    int j = idx - n1; int k = j / WPAD, c = j % WPAD;
    W2p[j] = (k < D_H && c < D_H) ? W2[k * D_H + c] : 0.0f;
  } else if (idx < n1 + n2 + TSH) {
    int c = idx - (n1 + n2);
    b1p[c] = (c < D_H) ? b1[c] : 0.0f;
  } else if (idx < n1 + n2 + 2 * TSH) {
    int c = idx - (n1 + n2 + TSH);
    b2p[c] = (c < D_H) ? b2[c] : 0.0f;
  }
}

// ---------- f32 tiled GEMM, fp16 output: C[N x TSH] = (A * Wp) * dinv[row] ----------
// IN_HALF: A is __half with row stride lda (in halves); else float.
template<int K, int KEFF, bool IN_HALF>
__global__ __launch_bounds__(256) void gemm_kernel(const void* __restrict__ Av, int lda,
                                                   const float* __restrict__ Wp,
                                                   const float* __restrict__ dinv,
                                                   __half* __restrict__ C, int N) {
  __shared__ float As[16][64];
  __shared__ float Ws[16][128];
  int tid = threadIdx.x;
  int row0 = blockIdx.x * 64;
  int tx = tid & 15, ty = tid >> 4;
  float acc[4][8];
  #pragma unroll
  for (int i = 0; i < 4; ++i)
    #pragma unroll
    for (int j = 0; j < 8; ++j) acc[i][j] = 0.0f;

  int ar  = tid >> 2;          // 0..63 row within tile
  int akq = (tid & 3) * 4;     // k offset 0,4,8,12
  int wc  = (tid & 31) * 4;    // 0..124
  int wk  = tid >> 5;          // 0..7

  for (int kb = 0; kb < K; kb += 16) {
    float2 a01 = make_float2(0.f, 0.f), a23 = make_float2(0.f, 0.f);
    int arow = row0 + ar;
    int k0 = kb + akq;
    if (arow < N) {
      if constexpr (IN_HALF) {
        const __half* A = (const __half*)Av;
        if (k0 < KEFF)     a01 = __half22float2(*(const __half2*)&A[(size_t)arow * lda + k0]);
        if (k0 + 2 < KEFF) a23 = __half22float2(*(const __half2*)&A[(size_t)arow * lda + k0 + 2]);
      } else {
        const float* A = (const float*)Av;
        if (k0 < KEFF)     a01 = *(const float2*)&A[(size_t)arow * lda + k0];
        if (k0 + 2 < KEFF) a23 = *(const float2*)&A[(size_t)arow * lda + k0 + 2];
      }
    }
    As[akq + 0][ar] = a01.x; As[akq + 1][ar] = a01.y;
    As[akq + 2][ar] = a23.x; As[akq + 3][ar] = a23.y;
    *(float4*)&Ws[wk][wc]     = *(const float4*)&Wp[(size_t)(kb + wk) * WPAD + wc];
    *(float4*)&Ws[wk + 8][wc] = *(const float4*)&Wp[(size_t)(kb + wk + 8) * WPAD + wc];
    __syncthreads();
    #pragma unroll
    for (int k = 0; k < 16; ++k) {
      float4 a4 = *(const float4*)&As[k][ty * 4];
      float4 wA = *(const float4*)&Ws[k][tx * 4];
      float4 wB = *(const float4*)&Ws[k][64 + tx * 4];
      float av[4] = {a4.x, a4.y, a4.z, a4.w};
      float wv[8] = {wA.x, wA.y, wA.z, wA.w, wB.x, wB.y, wB.z, wB.w};
      #pragma unroll
      for (int i = 0; i < 4; ++i)
        #pragma unroll
        for (int j = 0; j < 8; ++j) acc[i][j] += av[i] * wv[j];
    }
    __syncthreads();
  }
  #pragma unroll
  for (int i = 0; i < 4; ++i) {
    int r = row0 + ty * 4 + i;
    if (r >= N) continue;
    float dv = dinv[r];
    __half2* crow = (__half2*)(C + (size_t)r * TSH);
    int cA = tx * 4, cB = 64 + tx * 4;   // cA <= 60; cB <= 124
    crow[cA / 2]     = __floats2half2_rn(acc[i][0] * dv, acc[i][1] * dv);
    crow[cA / 2 + 1] = __floats2half2_rn(acc[i][2] * dv, acc[i][3] * dv);
    if (cB < D_H + 1)     crow[cB / 2]     = __floats2half2_rn(acc[i][4] * dv, acc[i][5] * dv);
    if (cB + 2 < D_H + 1) crow[cB / 2 + 1] = __floats2half2_rn(acc[i][6] * dv, acc[i][7] * dv);
  }
}

// ---------- CSR aggregation: one wave per destination node, fp16 gather, f32 accum ----------
// t rows are pre-scaled by dinv[src]; final scale by dinv[node] here.
template<bool OUT_HALF, bool DO_RELU>
__global__ __launch_bounds__(256) void agg_kernel(
    const __half* __restrict__ t, const int* __restrict__ csr_src,
    const int* __restrict__ row_start,
    const float* __restrict__ dinv, const float* __restrict__ bias,
    void* __restrict__ outp, int N) {
  int lane = threadIdx.x & 63;
  int node = blockIdx.x * (blockDim.x >> 6) + (threadIdx.x >> 6);
  if (node >= N || lane >= 49) return;   // 49 lanes x half2 = 98 cols (col 97 is zero pad)
  int s = row_start[node], epd = row_start[node + 1];
  float di = dinv[node];
  float2 v = __half22float2(((const __half2*)(t + (size_t)node * TSH))[lane]);
  float ax = v.x, ay = v.y;
  int e = s;
  for (; e + 4 <= epd; e += 4) {
    int j0 = csr_src[e], j1 = csr_src[e + 1], j2 = csr_src[e + 2], j3 = csr_src[e + 3];
    float2 u0 = __half22float2(((const __half2*)(t + (size_t)j0 * TSH))[lane]);
    float2 u1 = __half22float2(((const __half2*)(t + (size_t)j1 * TSH))[lane]);
    float2 u2 = __half22float2(((const __half2*)(t + (size_t)j2 * TSH))[lane]);
    float2 u3 = __half22float2(((const __half2*)(t + (size_t)j3 * TSH))[lane]);
    ax += u0.x; ay += u0.y;
    ax += u1.x; ay += u1.y;
    ax += u2.x; ay += u2.y;
    ax += u3.x; ay += u3.y;
  }
  for (; e < epd; ++e) {
    int j = csr_src[e];
    float2 u = __half22float2(((const __half2*)(t + (size_t)j * TSH))[lane]);
    ax += u.x; ay += u.y;
  }
  int c0 = 2 * lane, c1 = 2 * lane + 1;
  ax = ax * di + bias[c0];
  ay = ay * di + bias[c1];
  if (DO_RELU) { ax = fmaxf(ax, 0.f); ay = fmaxf(ay, 0.f); }
  if (OUT_HALF) {
    __half2* o = (__half2*)((__half*)outp + (size_t)node * TSH);
    o[lane] = __floats2half2_rn(ax, ay);
  } else {
    float* o = (float*)outp + (size_t)node * D_H;
    if (c0 < D_H) o[c0] = ax;
    if (c1 < D_H) o[c1] = ay;
  }
}

// ---------- launch ----------
extern "C" void kernel_launch(void* const* d_in, const int* in_sizes, int n_in,
                              void* d_out, int out_size, void* d_ws, size_t ws_size,
                              hipStream_t stream) {
  const float* x  = (const float*)d_in[0];
  const void*  ei = d_in[1];
  const float* W1 = (const float*)d_in[2];
  const float* b1 = (const float*)d_in[3];
  const float* W2 = (const float*)d_in[4];
  const float* b2 = (const float*)d_in[5];
  int N = in_sizes[0] / D_IN;
  long long E = (long long)in_sizes[1] / 2;
  int nbuck = (N + NPB - 1) / NPB;

  char* base = (char*)d_ws;
  size_t off = 0;
  auto alloc = [&](size_t bytes) -> void* {
    void* p = base + off;
    off = (off + bytes + 255) & ~(size_t)255;
    return p;
  };
  int*   flag      = (int*)alloc(4);
  float* dinv      = (float*)alloc((size_t)N * 4);
  int*   row_start = (int*)alloc((size_t)(N + 1) * 4);
  int*   bcnt      = (int*)alloc((size_t)(nbuck + 1) * 4);
  int*   bstart    = (int*)alloc((size_t)(nbuck + 1) * 4);
  int*   bcur      = (int*)alloc((size_t)(nbuck + 1) * 4);
  int*   csr_src   = (int*)alloc((size_t)E * 4);
  float* W1p       = (float*)alloc((size_t)256 * WPAD * 4);
  float* W2p       = (float*)alloc((size_t)112 * WPAD * 4);
  float* b1p       = (float*)alloc(TSH * 4);
  float* b2p       = (float*)alloc(TSH * 4);
  __half* t1       = (__half*)alloc((size_t)N * TSH * 2 + 256);
  __half* h1       = (__half*)alloc((size_t)N * TSH * 2 + 256);
  unsigned int* bsd = (unsigned int*)t1;   // aliases t1 (E*4 <= N*TSH*2): dead before gemm1 writes t1

  hipMemsetAsync(bcnt, 0, (size_t)(nbuck + 1) * 4, stream);
  detect_kernel<<<1, 256, 0, stream>>>(ei, E, flag);
  bucket_count<<<256, 256, 0, stream>>>(ei, flag, bcnt, E, nbuck);
  bucket_scan<<<1, 256, 0, stream>>>(bcnt, bstart, bcur, nbuck);
  bucket_scatter_staged<<<(int)((E + CHUNK - 1) / CHUNK), 256, 0, stream>>>(
      ei, flag, bcur, bsd, E, nbuck);
  bucket_finalize<<<nbuck, 256, 0, stream>>>(bsd, bstart, row_start, dinv, csr_src, N, E, nbuck);
  prep_kernel<<<(256 * WPAD + 112 * WPAD + 2 * TSH + 255) / 256, 256, 0, stream>>>(
      W1, b1, W2, b2, W1p, W2p, b1p, b2p);
  gemm_kernel<256, 256, false><<<(N + 63) / 64, 256, 0, stream>>>(x, D_IN, W1p, dinv, t1, N);
  agg_kernel<true, true><<<(N + 3) / 4, 256, 0, stream>>>(t1, csr_src, row_start, dinv, b1p, h1, N);
  gemm_kernel<112, 98, true><<<(N + 63) / 64, 256, 0, stream>>>(h1, TSH, W2p, dinv, t1, N);
  agg_kernel<false, false><<<(N + 3) / 4, 256, 0, stream>>>(t1, csr_src, row_start, dinv, b2p,
                                                            d_out, N);
}

// Round 7
// 440.838 us; speedup vs baseline: 2.2064x; 1.0929x over previous
//
#include <hip/hip_runtime.h>
#include <hip/hip_fp16.h>
#include <stdint.h>

#define D_IN 256
#define D_H  97
#define RST  96      // half-prec row stride for cols 0..95: 192 B = exactly 3 cache lines
#define WPAD 128     // padded weight column count
#define NPB  512     // nodes per coarse bucket (shift 9); src packs in 17 bits (N <= 131072)
#define NBMAX 256    // max coarse buckets
#define CHUNK 4096   // edges per scatter WG

// ---------- helpers ----------
__device__ __forceinline__ int load_idx(const void* p, int is64, long long pos) {
  if (is64) return (int)(((const long long*)p)[pos]);
  return ((const int*)p)[pos];
}

// Decide whether edge_index arrived as int64 (odd 32-bit words all zero) or int32.
__global__ void detect_kernel(const void* ei, long long E, int* flag) {
  const int* p32 = (const int*)ei;
  long long stride = E / 1024; if (stride < 1) stride = 1;
  int tid = threadIdx.x;
  int bad = 0;
  for (int s = 0; s < 4; ++s) {
    long long k = ((long long)tid * 4 + s) * stride;
    if (k < E) {
      if (p32[2 * k + 1] != 0) bad = 1;
    }
  }
  __shared__ int sh_bad;
  if (tid == 0) sh_bad = 0;
  __syncthreads();
  if (bad) atomicOr(&sh_bad, 1);
  __syncthreads();
  if (tid == 0) *flag = sh_bad ? 0 : 1;   // 1 => int64
}

// P1: chunked scatter with per-chunk bulk allocation into fixed-capacity bucket regions.
// One global atomic per (chunk,bucket); each WG owns a contiguous sub-range => clustered writes.
__global__ __launch_bounds__(256) void bucket_scatter_direct(
    const void* ei, const int* __restrict__ flag, int* __restrict__ bcur,
    unsigned int* __restrict__ bsd, long long E, int nbuck, int cap) {
  __shared__ unsigned int packs[CHUNK];
  __shared__ unsigned char bkts[CHUNK];
  __shared__ int hist[NBMAX];
  __shared__ int gpos[NBMAX];
  __shared__ int cur[NBMAX];
  int tid = threadIdx.x;
  if (tid < NBMAX) { hist[tid] = 0; cur[tid] = 0; }
  __syncthreads();
  int f = *flag;
  long long base = (long long)blockIdx.x * CHUNK;
  int cnt = (int)((E - base < CHUNK) ? (E - base) : CHUNK);
  #pragma unroll 4
  for (int i = tid; i < cnt; i += 256) {
    long long e = base + i;
    int s = load_idx(ei, f, e);
    int d = load_idx(ei, f, E + e);
    int b = d >> 9;
    packs[i] = ((unsigned int)(d & (NPB - 1)) << 17) | (unsigned int)s;
    bkts[i] = (unsigned char)b;
    atomicAdd(&hist[b], 1);
  }
  __syncthreads();
  if (tid < nbuck) { int h = hist[tid]; if (h) gpos[tid] = atomicAdd(&bcur[tid], h); }
  __syncthreads();
  #pragma unroll 4
  for (int i = tid; i < cnt; i += 256) {
    int b = bkts[i];
    int r = atomicAdd(&cur[b], 1);
    int idx = gpos[b] + r;
    if (idx < cap) bsd[(size_t)b * cap + idx] = packs[i];   // clamp: drop on (never-hit) overflow
  }
}

// P2: exclusive scan of actual bucket counts -> global CSR base per bucket
__global__ void bucket_scan2(const int* __restrict__ bcur, int* __restrict__ bstart,
                             int* __restrict__ row_start, int N, int nbuck, int cap) {
  __shared__ int sh[256];
  int tid = threadIdx.x;
  int v = (tid < nbuck) ? min(bcur[tid], cap) : 0;
  sh[tid] = v;
  __syncthreads();
  for (int off = 1; off < 256; off <<= 1) {
    int a = (tid >= off) ? sh[tid - off] : 0;
    __syncthreads();
    sh[tid] += a;
    __syncthreads();
  }
  if (tid < nbuck) bstart[tid] = sh[tid] - v;
  if (tid == 255) { bstart[nbuck] = sh[255]; row_start[N] = sh[255]; }
}

// P3: per-bucket finalize: node histogram -> prefix -> row_start + dinv -> CSR scatter.
__global__ __launch_bounds__(256) void bucket_finalize(
    const unsigned int* __restrict__ bsd, const int* __restrict__ bcur,
    const int* __restrict__ bstart,
    int* __restrict__ row_start, float* __restrict__ dinv,
    int* __restrict__ csr_src, int N, int cap) {
  __shared__ int h[NPB];
  __shared__ int rs[NPB];
  __shared__ int cur[NPB];
  __shared__ int wsum[4];
  int b = blockIdx.x, tid = threadIdx.x;
  int lane = tid & 63, wid = tid >> 6;
  h[2 * tid] = 0; h[2 * tid + 1] = 0;
  cur[2 * tid] = 0; cur[2 * tid + 1] = 0;
  __syncthreads();
  int d0 = b * cap;
  int cnt = min(bcur[b], cap);
  for (int i = tid; i < cnt; i += 256) atomicAdd(&h[bsd[d0 + i] >> 17], 1);
  __syncthreads();
  int a0 = h[2 * tid], a1 = h[2 * tid + 1];
  int tsum = a0 + a1;
  int incl = tsum;
  #pragma unroll
  for (int off = 1; off < 64; off <<= 1) {
    int n = __shfl_up(incl, off, 64);
    if (lane >= off) incl += n;
  }
  if (lane == 63) wsum[wid] = incl;
  __syncthreads();
  int woff = 0;
  for (int k = 0; k < wid; ++k) woff += wsum[k];
  int excl = woff + incl - tsum + bstart[b];
  rs[2 * tid] = excl;
  rs[2 * tid + 1] = excl + a0;
  int node0 = b * NPB;
  int n0 = node0 + 2 * tid, n1 = node0 + 2 * tid + 1;
  if (n0 < N) { row_start[n0] = excl;      dinv[n0] = rsqrtf((float)(a0 + 1)); }
  if (n1 < N) { row_start[n1] = excl + a0; dinv[n1] = rsqrtf((float)(a1 + 1)); }
  __syncthreads();
  for (int i = tid; i < cnt; i += 256) {
    unsigned int p = bsd[d0 + i];
    int r = p >> 17;
    int s = (int)(p & 0x1FFFFu);
    int rel = atomicAdd(&cur[r], 1);
    csr_src[rs[r] + rel] = s;
  }
}

// ---------- pad weights/biases ----------
__global__ void prep_kernel(const float* __restrict__ W1, const float* __restrict__ b1,
                            const float* __restrict__ W2, const float* __restrict__ b2,
                            float* __restrict__ W1p, float* __restrict__ W2p,
                            float* __restrict__ b1p, float* __restrict__ b2p) {
  int idx = blockIdx.x * blockDim.x + threadIdx.x;
  const int n1 = 256 * WPAD, n2 = 112 * WPAD;
  if (idx < n1) {
    int k = idx / WPAD, c = idx % WPAD;
    W1p[idx] = (c < D_H) ? W1[k * D_H + c] : 0.0f;
  } else if (idx < n1 + n2) {
    int j = idx - n1; int k = j / WPAD, c = j % WPAD;
    W2p[j] = (k < D_H && c < D_H) ? W2[k * D_H + c] : 0.0f;
  } else if (idx < n1 + n2 + 128) {
    int c = idx - (n1 + n2);
    b1p[c] = (c < D_H) ? b1[c] : 0.0f;
  } else if (idx < n1 + n2 + 256) {
    int c = idx - (n1 + n2 + 128);
    b2p[c] = (c < D_H) ? b2[c] : 0.0f;
  }
}

// ---------- f32 tiled GEMM, fp16 output in (96-stride + side-col) layout ----------
// C row r: cols 0..95 at C + r*RST; col 96 -> sideC[r].x (.y = 0)
template<int K, bool IN_HALF>
__global__ __launch_bounds__(256) void gemm_kernel(const void* __restrict__ Av,
                                                   const __half2* __restrict__ sideA,
                                                   const float* __restrict__ Wp,
                                                   const float* __restrict__ dinv,
                                                   __half* __restrict__ C,
                                                   __half2* __restrict__ sideC, int N) {
  __shared__ float As[16][64];
  __shared__ float Ws[16][128];
  int tid = threadIdx.x;
  int row0 = blockIdx.x * 64;
  int tx = tid & 15, ty = tid >> 4;
  float acc[4][8];
  #pragma unroll
  for (int i = 0; i < 4; ++i)
    #pragma unroll
    for (int j = 0; j < 8; ++j) acc[i][j] = 0.0f;

  int ar  = tid >> 2;          // 0..63 row within tile
  int akq = (tid & 3) * 4;     // k offset 0,4,8,12
  int wc  = (tid & 31) * 4;    // 0..124
  int wk  = tid >> 5;          // 0..7

  for (int kb = 0; kb < K; kb += 16) {
    float2 a01 = make_float2(0.f, 0.f), a23 = make_float2(0.f, 0.f);
    int arow = row0 + ar;
    int k0 = kb + akq;
    if (arow < N) {
      if constexpr (IN_HALF) {
        const __half* A = (const __half*)Av;
        if (k0 < 96) {        // k0 <= 92 here, so k0+3 <= 95 in-bounds
          a01 = __half22float2(*(const __half2*)&A[(size_t)arow * RST + k0]);
          a23 = __half22float2(*(const __half2*)&A[(size_t)arow * RST + k0 + 2]);
        } else if (k0 == 96) {
          a01.x = __half22float2(sideA[arow]).x;   // col 96; col 97+ are zero
        }
      } else {
        const float* A = (const float*)Av;
        a01 = *(const float2*)&A[(size_t)arow * K + k0];
        a23 = *(const float2*)&A[(size_t)arow * K + k0 + 2];
      }
    }
    As[akq + 0][ar] = a01.x; As[akq + 1][ar] = a01.y;
    As[akq + 2][ar] = a23.x; As[akq + 3][ar] = a23.y;
    *(float4*)&Ws[wk][wc]     = *(const float4*)&Wp[(size_t)(kb + wk) * WPAD + wc];
    *(float4*)&Ws[wk + 8][wc] = *(const float4*)&Wp[(size_t)(kb + wk + 8) * WPAD + wc];
    __syncthreads();
    #pragma unroll
    for (int k = 0; k < 16; ++k) {
      float4 a4 = *(const float4*)&As[k][ty * 4];
      float4 wA = *(const float4*)&Ws[k][tx * 4];
      float4 wB = *(const float4*)&Ws[k][64 + tx * 4];
      float av[4] = {a4.x, a4.y, a4.z, a4.w};
      float wv[8] = {wA.x, wA.y, wA.z, wA.w, wB.x, wB.y, wB.z, wB.w};
      #pragma unroll
      for (int i = 0; i < 4; ++i)
        #pragma unroll
        for (int j = 0; j < 8; ++j) acc[i][j] += av[i] * wv[j];
    }
    __syncthreads();
  }
  #pragma unroll
  for (int i = 0; i < 4; ++i) {
    int r = row0 + ty * 4 + i;
    if (r >= N) continue;
    float dv = dinv[r];
    __half2* crow = (__half2*)(C + (size_t)r * RST);
    int cA = tx * 4, cB = 64 + tx * 4;   // cA <= 60; cB <= 124
    crow[cA / 2]     = __floats2half2_rn(acc[i][0] * dv, acc[i][1] * dv);
    crow[cA / 2 + 1] = __floats2half2_rn(acc[i][2] * dv, acc[i][3] * dv);
    if (cB < 96) {                        // cB <= 92 -> cols cB..cB+3 all < 96
      crow[cB / 2]     = __floats2half2_rn(acc[i][4] * dv, acc[i][5] * dv);
      crow[cB / 2 + 1] = __floats2half2_rn(acc[i][6] * dv, acc[i][7] * dv);
    } else if (cB == 96) {
      sideC[r] = __floats2half2_rn(acc[i][4] * dv, 0.f);   // col 96
    }
  }
}

// ---------- CSR aggregation: one wave per destination node, fp16 gather, f32 accum ----------
// Lanes 0-47 gather half2 (cols 2l,2l+1) from 192 B rows; lane 48 gathers col 96 from side.
template<bool OUT_HALF, bool DO_RELU>
__global__ __launch_bounds__(256) void agg_kernel(
    const __half* __restrict__ t, const __half2* __restrict__ side,
    const int* __restrict__ csr_src, const int* __restrict__ row_start,
    const float* __restrict__ dinv, const float* __restrict__ bias,
    void* __restrict__ outp, __half2* __restrict__ side_out, int N) {
  int lane = threadIdx.x & 63;
  int node = blockIdx.x * (blockDim.x >> 6) + (threadIdx.x >> 6);
  if (node >= N || lane >= 49) return;
  const char* gbase = (lane < 48) ? (const char*)t + lane * 4 : (const char*)side;
  unsigned gscale = (lane < 48) ? (unsigned)(RST * 2) : 4u;
  auto GATHER = [&](int j) -> float2 {
    return __half22float2(*(const __half2*)(gbase + (size_t)((unsigned)j * gscale)));
  };
  int s = row_start[node], epd = row_start[node + 1];
  float di = dinv[node];
  float2 v = GATHER(node);           // self term (already x dinv[node])
  float ax = v.x, ay = v.y;
  int e = s;
  while ((e & 3) && e < epd) {       // align to 16 B for int4 edge loads
    float2 u = GATHER(csr_src[e]);
    ax += u.x; ay += u.y; ++e;
  }
  for (; e + 8 <= epd; e += 8) {
    int4 q0 = *(const int4*)(csr_src + e);
    int4 q1 = *(const int4*)(csr_src + e + 4);
    float2 u0 = GATHER(q0.x), u1 = GATHER(q0.y), u2 = GATHER(q0.z), u3 = GATHER(q0.w);
    float2 u4 = GATHER(q1.x), u5 = GATHER(q1.y), u6 = GATHER(q1.z), u7 = GATHER(q1.w);
    ax += ((u0.x + u1.x) + (u2.x + u3.x)) + ((u4.x + u5.x) + (u6.x + u7.x));
    ay += ((u0.y + u1.y) + (u2.y + u3.y)) + ((u4.y + u5.y) + (u6.y + u7.y));
  }
  if (e + 4 <= epd) {
    int4 q0 = *(const int4*)(csr_src + e);
    float2 u0 = GATHER(q0.x), u1 = GATHER(q0.y), u2 = GATHER(q0.z), u3 = GATHER(q0.w);
    ax += (u0.x + u1.x) + (u2.x + u3.x);
    ay += (u0.y + u1.y) + (u2.y + u3.y);
    e += 4;
  }
  for (; e < epd; ++e) {
    float2 u = GATHER(csr_src[e]);
    ax += u.x; ay += u.y;
  }
  int c0 = 2 * lane;                 // lane 48 -> c0 = 96
  ax = ax * di + bias[c0];
  ay = ay * di + bias[c0 + 1];       // bias[97] = 0 pad
  if (DO_RELU) { ax = fmaxf(ax, 0.f); ay = fmaxf(ay, 0.f); }
  if (OUT_HALF) {
    if (lane < 48) ((__half2*)((__half*)outp + (size_t)node * RST))[lane] = __floats2half2_rn(ax, ay);
    else           side_out[node] = __floats2half2_rn(ax, 0.f);
  } else {
    float* o = (float*)outp + (size_t)node * D_H;
    if (lane < 48) { o[c0] = ax; o[c0 + 1] = ay; }
    else           o[96] = ax;
  }
}

// ---------- launch ----------
extern "C" void kernel_launch(void* const* d_in, const int* in_sizes, int n_in,
                              void* d_out, int out_size, void* d_ws, size_t ws_size,
                              hipStream_t stream) {
  const float* x  = (const float*)d_in[0];
  const void*  ei = d_in[1];
  const float* W1 = (const float*)d_in[2];
  const float* b1 = (const float*)d_in[3];
  const float* W2 = (const float*)d_in[4];
  const float* b2 = (const float*)d_in[5];
  int N = in_sizes[0] / D_IN;
  long long E = (long long)in_sizes[1] / 2;
  int nbuck = (N + NPB - 1) / NPB;
  int cap = (int)(E / nbuck) + 8192;   // uniform-random slack >> 6 sigma

  char* base = (char*)d_ws;
  size_t off = 0;
  auto alloc = [&](size_t bytes) -> void* {
    void* p = base + off;
    off = (off + bytes + 255) & ~(size_t)255;
    return p;
  };
  int*    flag      = (int*)alloc(4);
  float*  dinv      = (float*)alloc((size_t)N * 4);
  int*    row_start = (int*)alloc((size_t)(N + 1) * 4);
  int*    bcur      = (int*)alloc((size_t)(nbuck + 1) * 4);
  int*    bstart    = (int*)alloc((size_t)(nbuck + 1) * 4);
  int*    csr_src   = (int*)alloc((size_t)E * 4);
  unsigned int* bsd = (unsigned int*)alloc((size_t)nbuck * cap * 4);
  float*  W1p       = (float*)alloc((size_t)256 * WPAD * 4);
  float*  W2p       = (float*)alloc((size_t)112 * WPAD * 4);
  float*  b1p       = (float*)alloc(128 * 4);
  float*  b2p       = (float*)alloc(128 * 4);
  __half* t1        = (__half*)alloc((size_t)N * RST * 2 + 256);
  __half2* sideT    = (__half2*)alloc((size_t)N * 4 + 256);
  __half* h1        = (__half*)alloc((size_t)N * RST * 2 + 256);
  __half2* sideH    = (__half2*)alloc((size_t)N * 4 + 256);

  hipMemsetAsync(bcur, 0, (size_t)(nbuck + 1) * 4, stream);
  detect_kernel<<<1, 256, 0, stream>>>(ei, E, flag);
  bucket_scatter_direct<<<(int)((E + CHUNK - 1) / CHUNK), 256, 0, stream>>>(
      ei, flag, bcur, bsd, E, nbuck, cap);
  bucket_scan2<<<1, 256, 0, stream>>>(bcur, bstart, row_start, N, nbuck, cap);
  bucket_finalize<<<nbuck, 256, 0, stream>>>(bsd, bcur, bstart, row_start, dinv, csr_src, N, cap);
  prep_kernel<<<(256 * WPAD + 112 * WPAD + 256 + 255) / 256, 256, 0, stream>>>(
      W1, b1, W2, b2, W1p, W2p, b1p, b2p);
  gemm_kernel<256, false><<<(N + 63) / 64, 256, 0, stream>>>(x, nullptr, W1p, dinv, t1, sideT, N);
  agg_kernel<true, true><<<(N + 3) / 4, 256, 0, stream>>>(t1, sideT, csr_src, row_start,
                                                          dinv, b1p, h1, sideH, N);
  gemm_kernel<112, true><<<(N + 63) / 64, 256, 0, stream>>>(h1, sideH, W2p, dinv, t1, sideT, N);
  agg_kernel<false, false><<<(N + 3) / 4, 256, 0, stream>>>(t1, sideT, csr_src, row_start,
                                                            dinv, b2p, d_out, nullptr, N);
}

// Round 8
// 374.925 us; speedup vs baseline: 2.5942x; 1.1758x over previous
//
#include <hip/hip_runtime.h>
#include <hip/hip_fp16.h>
#include <stdint.h>

#define D_IN 256
#define D_H  97
#define RST  96      // half-prec row stride for cols 0..95: 192 B = exactly 3 cache lines
#define NPB  512     // nodes per coarse bucket (shift 9); src packs in 17 bits (N <= 131072)
#define NBMAX 256    // max coarse buckets
#define CHUNK 4096   // edges per scatter WG
#define KP1  264     // LDS/global k-stride for W1^T (256 + 8 pad)
#define KP2  136     // LDS/global k-stride for W2^T (128 + 8 pad)

typedef _Float16 f16;
typedef f16   f16x8 __attribute__((ext_vector_type(8)));
typedef float f32x4 __attribute__((ext_vector_type(4)));

// ---------- helpers ----------
__device__ __forceinline__ int load_idx(const void* p, int is64, long long pos) {
  if (is64) return (int)(((const long long*)p)[pos]);
  return ((const int*)p)[pos];
}

// Decide whether edge_index arrived as int64 (odd 32-bit words all zero) or int32.
__global__ void detect_kernel(const void* ei, long long E, int* flag) {
  const int* p32 = (const int*)ei;
  long long stride = E / 1024; if (stride < 1) stride = 1;
  int tid = threadIdx.x;
  int bad = 0;
  for (int s = 0; s < 4; ++s) {
    long long k = ((long long)tid * 4 + s) * stride;
    if (k < E) {
      if (p32[2 * k + 1] != 0) bad = 1;
    }
  }
  __shared__ int sh_bad;
  if (tid == 0) sh_bad = 0;
  __syncthreads();
  if (bad) atomicOr(&sh_bad, 1);
  __syncthreads();
  if (tid == 0) *flag = sh_bad ? 0 : 1;   // 1 => int64
}

// P1: chunked scatter with per-chunk bulk allocation into fixed-capacity bucket regions.
__global__ __launch_bounds__(256) void bucket_scatter_direct(
    const void* ei, const int* __restrict__ flag, int* __restrict__ bcur,
    unsigned int* __restrict__ bsd, long long E, int nbuck, int cap) {
  __shared__ unsigned int packs[CHUNK];
  __shared__ unsigned char bkts[CHUNK];
  __shared__ int hist[NBMAX];
  __shared__ int gpos[NBMAX];
  __shared__ int cur[NBMAX];
  int tid = threadIdx.x;
  if (tid < NBMAX) { hist[tid] = 0; cur[tid] = 0; }
  __syncthreads();
  int f = *flag;
  long long base = (long long)blockIdx.x * CHUNK;
  int cnt = (int)((E - base < CHUNK) ? (E - base) : CHUNK);
  #pragma unroll 4
  for (int i = tid; i < cnt; i += 256) {
    long long e = base + i;
    int s = load_idx(ei, f, e);
    int d = load_idx(ei, f, E + e);
    int b = d >> 9;
    packs[i] = ((unsigned int)(d & (NPB - 1)) << 17) | (unsigned int)s;
    bkts[i] = (unsigned char)b;
    atomicAdd(&hist[b], 1);
  }
  __syncthreads();
  if (tid < nbuck) { int h = hist[tid]; if (h) gpos[tid] = atomicAdd(&bcur[tid], h); }
  __syncthreads();
  #pragma unroll 4
  for (int i = tid; i < cnt; i += 256) {
    int b = bkts[i];
    int r = atomicAdd(&cur[b], 1);
    int idx = gpos[b] + r;
    if (idx < cap) bsd[(size_t)b * cap + idx] = packs[i];   // clamp: drop on (never-hit) overflow
  }
}

// P2: exclusive scan of actual bucket counts -> global CSR base per bucket
__global__ void bucket_scan2(const int* __restrict__ bcur, int* __restrict__ bstart,
                             int* __restrict__ row_start, int N, int nbuck, int cap) {
  __shared__ int sh[256];
  int tid = threadIdx.x;
  int v = (tid < nbuck) ? min(bcur[tid], cap) : 0;
  sh[tid] = v;
  __syncthreads();
  for (int off = 1; off < 256; off <<= 1) {
    int a = (tid >= off) ? sh[tid - off] : 0;
    __syncthreads();
    sh[tid] += a;
    __syncthreads();
  }
  if (tid < nbuck) bstart[tid] = sh[tid] - v;
  if (tid == 255) { bstart[nbuck] = sh[255]; row_start[N] = sh[255]; }
}

// P3: per-bucket finalize: node histogram -> prefix -> row_start + dinv -> CSR scatter.
__global__ __launch_bounds__(256) void bucket_finalize(
    const unsigned int* __restrict__ bsd, const int* __restrict__ bcur,
    const int* __restrict__ bstart,
    int* __restrict__ row_start, float* __restrict__ dinv,
    int* __restrict__ csr_src, int N, int cap) {
  __shared__ int h[NPB];
  __shared__ int rs[NPB];
  __shared__ int cur[NPB];
  __shared__ int wsum[4];
  int b = blockIdx.x, tid = threadIdx.x;
  int lane = tid & 63, wid = tid >> 6;
  h[2 * tid] = 0; h[2 * tid + 1] = 0;
  cur[2 * tid] = 0; cur[2 * tid + 1] = 0;
  __syncthreads();
  int d0 = b * cap;
  int cnt = min(bcur[b], cap);
  for (int i = tid; i < cnt; i += 256) atomicAdd(&h[bsd[d0 + i] >> 17], 1);
  __syncthreads();
  int a0 = h[2 * tid], a1 = h[2 * tid + 1];
  int tsum = a0 + a1;
  int incl = tsum;
  #pragma unroll
  for (int off = 1; off < 64; off <<= 1) {
    int n = __shfl_up(incl, off, 64);
    if (lane >= off) incl += n;
  }
  if (lane == 63) wsum[wid] = incl;
  __syncthreads();
  int woff = 0;
  for (int k = 0; k < wid; ++k) woff += wsum[k];
  int excl = woff + incl - tsum + bstart[b];
  rs[2 * tid] = excl;
  rs[2 * tid + 1] = excl + a0;
  int node0 = b * NPB;
  int n0 = node0 + 2 * tid, n1 = node0 + 2 * tid + 1;
  if (n0 < N) { row_start[n0] = excl;      dinv[n0] = rsqrtf((float)(a0 + 1)); }
  if (n1 < N) { row_start[n1] = excl + a0; dinv[n1] = rsqrtf((float)(a1 + 1)); }
  __syncthreads();
  for (int i = tid; i < cnt; i += 256) {
    unsigned int p = bsd[d0 + i];
    int r = p >> 17;
    int s = (int)(p & 0x1FFFFu);
    int rel = atomicAdd(&cur[r], 1);
    csr_src[rs[r] + rel] = s;
  }
}

// ---------- prep: transpose weights to fp16 [112][KP] (zero-padded), pad biases ----------
__global__ void prep_kernel(const float* __restrict__ W1, const float* __restrict__ b1,
                            const float* __restrict__ W2, const float* __restrict__ b2,
                            f16* __restrict__ W1t, f16* __restrict__ W2t,
                            float* __restrict__ b1p, float* __restrict__ b2p) {
  int idx = blockIdx.x * blockDim.x + threadIdx.x;
  const int n1 = 112 * KP1, n2 = 112 * KP2;
  if (idx < n1) {
    int c = idx / KP1, k = idx % KP1;
    W1t[idx] = (f16)((c < D_H && k < 256) ? W1[k * D_H + c] : 0.f);
  } else if (idx < n1 + n2) {
    int j = idx - n1; int c = j / KP2, k = j % KP2;
    W2t[j] = (f16)((c < D_H && k < D_H) ? W2[k * D_H + c] : 0.f);
  } else if (idx < n1 + n2 + 128) {
    int c = idx - (n1 + n2);
    b1p[c] = (c < D_H) ? b1[c] : 0.0f;
  } else if (idx < n1 + n2 + 256) {
    int c = idx - (n1 + n2 + 128);
    b2p[c] = (c < D_H) ? b2[c] : 0.0f;
  }
}

// ---------- MFMA fp16 GEMM: C[N x 112] = (A * W^T) * dinv[row], fp16 out (96-stride + side) ----------
// Block: 256 thr = 4 waves, 128 rows; wave w owns rows w*32..w*32+31 (2 row-groups of 16).
// KI k-iters of 32; B = W^T [112][KP] staged fully in LDS once; A staged per iter (f32->fp16 or fp16).
template<int KI, int KP, bool IN_HALF>
__global__ __launch_bounds__(256) void mfma_gemm(
    const void* __restrict__ Av, const __half2* __restrict__ sideA,
    const f16* __restrict__ Wt, const float* __restrict__ dinv,
    __half* __restrict__ C, __half2* __restrict__ sideC, int N) {
  __shared__ f16 Bs[112 * KP];
  __shared__ f16 As[128 * 40];      // k-stride 40 halves (80 B): 2-way-max bank aliasing
  int tid = threadIdx.x;
  int wave = tid >> 6, lane = tid & 63;
  int row0 = blockIdx.x * 128;

  for (int i = tid * 8; i < 112 * KP; i += 2048)
    *(f16x8*)&Bs[i] = *(const f16x8*)&Wt[i];

  f32x4 acc[2][7];
  #pragma unroll
  for (int mg = 0; mg < 2; ++mg)
    #pragma unroll
    for (int cg = 0; cg < 7; ++cg)
      #pragma unroll
      for (int j = 0; j < 4; ++j) acc[mg][cg][j] = 0.f;

  for (int kb = 0; kb < KI; ++kb) {
    if (kb) __syncthreads();
    int k0 = kb * 32;
    if constexpr (!IN_HALF) {
      #pragma unroll
      for (int ii = 0; ii < 4; ++ii) {
        int i = tid + ii * 256;          // 0..1023
        int row = i >> 3, col = (i & 7) * 4;
        int gr = row0 + row;
        float4 v = make_float4(0.f, 0.f, 0.f, 0.f);
        if (gr < N) v = *(const float4*)&((const float*)Av)[(size_t)gr * 256 + k0 + col];
        __half2* dst = (__half2*)&As[row * 40 + col];
        dst[0] = __floats2half2_rn(v.x, v.y);
        dst[1] = __floats2half2_rn(v.z, v.w);
      }
    } else {
      if (kb < KI - 1) {
        #pragma unroll
        for (int ii = 0; ii < 2; ++ii) {
          int i = tid + ii * 256;        // 0..511
          int row = i >> 2, col = (i & 3) * 8;
          int gr = row0 + row;
          f16x8 v;
          #pragma unroll
          for (int q = 0; q < 8; ++q) v[q] = (f16)0.f;
          if (gr < N) v = *(const f16x8*)&((const f16*)Av)[(size_t)gr * RST + k0 + col];
          *(f16x8*)&As[row * 40 + col] = v;
        }
      } else {
        // last k-iter: k=96 is the side column, k=97..127 are zero
        if (tid < 128) {
          int gr = row0 + tid;
          f16 sv = (f16)0.f;
          if (gr < N) sv = ((const f16*)sideA)[2 * gr];
          f16* dst = &As[tid * 40];
          #pragma unroll
          for (int q = 0; q < 32; ++q) dst[q] = (f16)0.f;
          dst[0] = sv;
        }
      }
    }
    __syncthreads();
    int rbase = wave * 32 + (lane & 15);
    int kf = (lane >> 4) * 8;
    f16x8 a0 = *(const f16x8*)&As[rbase * 40 + kf];
    f16x8 a1 = *(const f16x8*)&As[(rbase + 16) * 40 + kf];
    #pragma unroll
    for (int cg = 0; cg < 7; ++cg) {
      f16x8 b = *(const f16x8*)&Bs[(cg * 16 + (lane & 15)) * KP + k0 + kf];
      acc[0][cg] = __builtin_amdgcn_mfma_f32_16x16x32_f16(a0, b, acc[0][cg], 0, 0, 0);
      acc[1][cg] = __builtin_amdgcn_mfma_f32_16x16x32_f16(a1, b, acc[1][cg], 0, 0, 0);
    }
  }
  // epilogue: C/D mapping col=lane&15, row=(lane>>4)*4+j  [HW-verified m89]
  int colb = lane & 15, rq = (lane >> 4) * 4;
  #pragma unroll
  for (int mg = 0; mg < 2; ++mg) {
    #pragma unroll
    for (int j = 0; j < 4; ++j) {
      int r = row0 + wave * 32 + mg * 16 + rq + j;
      if (r >= N) continue;
      float dv = dinv[r];
      #pragma unroll
      for (int cg = 0; cg < 7; ++cg) {
        int c = cg * 16 + colb;
        float val = acc[mg][cg][j] * dv;
        if (c < 96)       C[(size_t)r * RST + c] = __float2half(val);
        else if (c == 96) sideC[r] = __floats2half2_rn(val, 0.f);
      }
    }
  }
}

// ---------- CSR aggregation (unchanged from round 7) ----------
template<bool OUT_HALF, bool DO_RELU>
__global__ __launch_bounds__(256) void agg_kernel(
    const __half* __restrict__ t, const __half2* __restrict__ side,
    const int* __restrict__ csr_src, const int* __restrict__ row_start,
    const float* __restrict__ dinv, const float* __restrict__ bias,
    void* __restrict__ outp, __half2* __restrict__ side_out, int N) {
  int lane = threadIdx.x & 63;
  int node = blockIdx.x * (blockDim.x >> 6) + (threadIdx.x >> 6);
  if (node >= N || lane >= 49) return;
  const char* gbase = (lane < 48) ? (const char*)t + lane * 4 : (const char*)side;
  unsigned gscale = (lane < 48) ? (unsigned)(RST * 2) : 4u;
  auto GATHER = [&](int j) -> float2 {
    return __half22float2(*(const __half2*)(gbase + (size_t)((unsigned)j * gscale)));
  };
  int s = row_start[node], epd = row_start[node + 1];
  float di = dinv[node];
  float2 v = GATHER(node);           // self term (already x dinv[node])
  float ax = v.x, ay = v.y;
  int e = s;
  while ((e & 3) && e < epd) {
    float2 u = GATHER(csr_src[e]);
    ax += u.x; ay += u.y; ++e;
  }
  for (; e + 8 <= epd; e += 8) {
    int4 q0 = *(const int4*)(csr_src + e);
    int4 q1 = *(const int4*)(csr_src + e + 4);
    float2 u0 = GATHER(q0.x), u1 = GATHER(q0.y), u2 = GATHER(q0.z), u3 = GATHER(q0.w);
    float2 u4 = GATHER(q1.x), u5 = GATHER(q1.y), u6 = GATHER(q1.z), u7 = GATHER(q1.w);
    ax += ((u0.x + u1.x) + (u2.x + u3.x)) + ((u4.x + u5.x) + (u6.x + u7.x));
    ay += ((u0.y + u1.y) + (u2.y + u3.y)) + ((u4.y + u5.y) + (u6.y + u7.y));
  }
  if (e + 4 <= epd) {
    int4 q0 = *(const int4*)(csr_src + e);
    float2 u0 = GATHER(q0.x), u1 = GATHER(q0.y), u2 = GATHER(q0.z), u3 = GATHER(q0.w);
    ax += (u0.x + u1.x) + (u2.x + u3.x);
    ay += (u0.y + u1.y) + (u2.y + u3.y);
    e += 4;
  }
  for (; e < epd; ++e) {
    float2 u = GATHER(csr_src[e]);
    ax += u.x; ay += u.y;
  }
  int c0 = 2 * lane;                 // lane 48 -> c0 = 96
  ax = ax * di + bias[c0];
  ay = ay * di + bias[c0 + 1];
  if (DO_RELU) { ax = fmaxf(ax, 0.f); ay = fmaxf(ay, 0.f); }
  if (OUT_HALF) {
    if (lane < 48) ((__half2*)((__half*)outp + (size_t)node * RST))[lane] = __floats2half2_rn(ax, ay);
    else           side_out[node] = __floats2half2_rn(ax, 0.f);
  } else {
    float* o = (float*)outp + (size_t)node * D_H;
    if (lane < 48) { o[c0] = ax; o[c0 + 1] = ay; }
    else           o[96] = ax;
  }
}

// ---------- launch ----------
extern "C" void kernel_launch(void* const* d_in, const int* in_sizes, int n_in,
                              void* d_out, int out_size, void* d_ws, size_t ws_size,
                              hipStream_t stream) {
  const float* x  = (const float*)d_in[0];
  const void*  ei = d_in[1];
  const float* W1 = (const float*)d_in[2];
  const float* b1 = (const float*)d_in[3];
  const float* W2 = (const float*)d_in[4];
  const float* b2 = (const float*)d_in[5];
  int N = in_sizes[0] / D_IN;
  long long E = (long long)in_sizes[1] / 2;
  int nbuck = (N + NPB - 1) / NPB;
  int cap = (int)(E / nbuck) + 8192;   // uniform-random slack >> 6 sigma

  char* base = (char*)d_ws;
  size_t off = 0;
  auto alloc = [&](size_t bytes) -> void* {
    void* p = base + off;
    off = (off + bytes + 255) & ~(size_t)255;
    return p;
  };
  int*    flag      = (int*)alloc(4);
  float*  dinv      = (float*)alloc((size_t)N * 4);
  int*    row_start = (int*)alloc((size_t)(N + 1) * 4);
  int*    bcur      = (int*)alloc((size_t)(nbuck + 1) * 4);
  int*    bstart    = (int*)alloc((size_t)(nbuck + 1) * 4);
  int*    csr_src   = (int*)alloc((size_t)E * 4);
  unsigned int* bsd = (unsigned int*)alloc((size_t)nbuck * cap * 4);
  f16*    W1t       = (f16*)alloc((size_t)112 * KP1 * 2);
  f16*    W2t       = (f16*)alloc((size_t)112 * KP2 * 2);
  float*  b1p       = (float*)alloc(128 * 4);
  float*  b2p       = (float*)alloc(128 * 4);
  __half* t1        = (__half*)alloc((size_t)N * RST * 2 + 256);
  __half2* sideT    = (__half2*)alloc((size_t)N * 4 + 256);
  __half* h1        = (__half*)alloc((size_t)N * RST * 2 + 256);
  __half2* sideH    = (__half2*)alloc((size_t)N * 4 + 256);

  hipMemsetAsync(bcur, 0, (size_t)(nbuck + 1) * 4, stream);
  detect_kernel<<<1, 256, 0, stream>>>(ei, E, flag);
  bucket_scatter_direct<<<(int)((E + CHUNK - 1) / CHUNK), 256, 0, stream>>>(
      ei, flag, bcur, bsd, E, nbuck, cap);
  bucket_scan2<<<1, 256, 0, stream>>>(bcur, bstart, row_start, N, nbuck, cap);
  bucket_finalize<<<nbuck, 256, 0, stream>>>(bsd, bcur, bstart, row_start, dinv, csr_src, N, cap);
  prep_kernel<<<(112 * KP1 + 112 * KP2 + 256 + 255) / 256, 256, 0, stream>>>(
      W1, b1, W2, b2, W1t, W2t, b1p, b2p);
  mfma_gemm<8, KP1, false><<<(N + 127) / 128, 256, 0, stream>>>(
      x, nullptr, W1t, dinv, t1, sideT, N);
  agg_kernel<true, true><<<(N + 3) / 4, 256, 0, stream>>>(t1, sideT, csr_src, row_start,
                                                          dinv, b1p, h1, sideH, N);
  mfma_gemm<4, KP2, true><<<(N + 127) / 128, 256, 0, stream>>>(
      h1, sideH, W2t, dinv, t1, sideT, N);
  agg_kernel<false, false><<<(N + 3) / 4, 256, 0, stream>>>(t1, sideT, csr_src, row_start,
                                                            dinv, b2p, d_out, nullptr, N);
}